// Round 6
// baseline (842.687 us; speedup 1.0000x reference)
//
#include <hip/hip_runtime.h>
#include <cstdint>
#include <cstddef>

// ---------------------------------------------------------------------------
// Graph_8564164788735: 2-layer class-conditioned GRU-ish propagation.
// N=1024 nodes, C=128 classes, H=256. Output fp32 [N,C,H].
//
// R11: l2's latency-bound As-prep (sigm(SG4+PRE4)*H1 per K-step, serialized
// against MFMA by barriers -> MfmaUtil 3.5%) is MOVED into gemm_pre's ct==1
// epilogue: the store loop now writes RH = sigm(SG4+acc)*H1 into PRE's
// gate-4 slot (same bytes l2 reads; numerics identical). gemm_l2 becomes a
// clone of the proven R9 4-phase 256x256/512-thread counted-vmcnt pipeline
// (nkt=4, A=RH via global_load_lds, B=u5b) with a two-pass f32 LDS
// transpose epilogue (L[128][256] word-XOR swizzle, exactly 128 KiB) for
// vectorized z/pv/out. gemm_pre gains SG/H1 epilogue reads (~+64MB).
// ---------------------------------------------------------------------------

#define NODES 1024
#define NCLS  128
#define HID   256

using frag  = __attribute__((ext_vector_type(8))) short;
using frag4 = __attribute__((ext_vector_type(4))) short;
using f32x4 = __attribute__((ext_vector_type(4))) float;

__device__ __forceinline__ float bf2f(unsigned short h){
  unsigned int u = ((unsigned int)h) << 16;
  float f; __builtin_memcpy(&f, &u, 4); return f;
}
__device__ __forceinline__ unsigned short f2bf(float f){
  unsigned int u; __builtin_memcpy(&u, &f, 4);
  u = (u + 0x7fffu + ((u >> 16) & 1u)) >> 16;   // RNE
  return (unsigned short)u;
}
__device__ __forceinline__ float sigm(float x){ return 1.0f/(1.0f + __expf(-x)); }
__device__ __forceinline__ float tanh_fast(float x){ return 1.0f - 2.0f/(__expf(2.0f*x) + 1.0f); }

#define GLOBAL_AS(p) ((const __attribute__((address_space(1))) void*)(p))
#define LDS_AS(p)    ((__attribute__((address_space(3))) void*)(p))
#define MFMA16 __builtin_amdgcn_mfma_f32_16x16x32_bf16

// ---------------------------------------------------------------------------
// Generic bf16 MFMA GEMM (only used for XW). 128x128 tile, BK=32.
// ---------------------------------------------------------------------------
template<int OUT_BF16>
__global__ __launch_bounds__(256) void gemm_bf16(
    const unsigned short* __restrict__ A0, int ldA0, int K0,
    const unsigned short* __restrict__ A1, int ldA1,
    const unsigned short* __restrict__ BT, int ldB, long bStride,
    void* __restrict__ Cptr, int ldC,
    int Ntiles, int Ktot, unsigned int aMask, int Mtiles)
{
  __shared__ unsigned short As[4096];
  __shared__ unsigned short Bs[4096];
  const int t   = threadIdx.x;
  const int bid = blockIdx.x;
  const int xcd = bid & 7, slot = bid >> 3;
  const int mtPerX = (Mtiles >= 8) ? (Mtiles >> 3) : 1;
  const int mt = xcd * mtPerX + slot / Ntiles;
  const int nt = slot % Ntiles;
  const int lane = t & 63, w = t >> 6;
  const int wm = w >> 1, wn = w & 1;
  const int r = lane & 15, q = lane >> 4;
  const int m0 = mt * 128, n0 = nt * 128;
  const unsigned short* Bbase = BT + (size_t)mt * (size_t)bStride;

  f32x4 acc[4][4] = {};

  for (int kb = 0; kb < Ktot; kb += 32) {
#pragma unroll
    for (int i = 0; i < 2; ++i) {
      int u  = i * 256 + t;
      int mi = u >> 2;
      int kc = (u & 3) * 8;
      int k  = kb + kc;
      const unsigned short* ga;
      if (k < K0) ga = A0 + (size_t)((unsigned int)(m0 + mi) & aMask) * (size_t)ldA0 + k;
      else        ga = A1 + (size_t)(m0 + mi) * (size_t)ldA1 + (k - K0);
      __builtin_amdgcn_global_load_lds(GLOBAL_AS(ga), LDS_AS(&As[u * 8]), 16, 0, 0);
      const unsigned short* gb = Bbase + (size_t)(n0 + mi) * (size_t)ldB + k;
      __builtin_amdgcn_global_load_lds(GLOBAL_AS(gb), LDS_AS(&Bs[u * 8]), 16, 0, 0);
    }
    __syncthreads();

    frag af[4], bf_[4];
#pragma unroll
    for (int x = 0; x < 4; ++x) {
      af[x]  = *(const frag*)&As[(wm * 64 + x * 16 + r) * 32 + q * 8];
      bf_[x] = *(const frag*)&Bs[(wn * 64 + x * 16 + r) * 32 + q * 8];
    }
#pragma unroll
    for (int x = 0; x < 4; ++x)
#pragma unroll
      for (int y = 0; y < 4; ++y)
        acc[x][y] = MFMA16(af[x], bf_[y], acc[x][y], 0, 0, 0);
    __syncthreads();
  }

#pragma unroll
  for (int x = 0; x < 4; ++x) {
#pragma unroll
    for (int y = 0; y < 4; ++y) {
      int col = n0 + wn * 64 + y * 16 + r;
#pragma unroll
      for (int g = 0; g < 4; ++g) {
        long row = m0 + wm * 64 + x * 16 + q * 4 + g;
        if (OUT_BF16) ((unsigned short*)Cptr)[row * (long)ldC + col] = f2bf(acc[x][y][g]);
        else          ((float*)Cptr)[row * (long)ldC + col] = acc[x][y][g];
      }
    }
  }
}

// ---------------------------------------------------------------------------
// gemm_pre (R11): R9 4-phase pipeline; ct==1 epilogue fuses l2's As-prep:
// RH = sigm(SG4 + pre4) * H1, written into PRE's gate-4 slot.
// ---------------------------------------------------------------------------
__global__ __launch_bounds__(512, 2) void gemm_pre(
    const unsigned short* __restrict__ AVH, const unsigned short* __restrict__ H1,
    const unsigned short* __restrict__ WB, const float* __restrict__ SG,
    unsigned short* __restrict__ PRE)
{
  __shared__ __align__(16) unsigned short SM[65536];   // 128 KiB
  const int t   = threadIdx.x;
  const int bid = blockIdx.x;
  const int xcd = bid & 7, slot = bid >> 3;
  const int mt = xcd * 64 + slot / 3;
  const int ct = slot % 3;
  const int lane = t & 63, w = t >> 6;
  const int wm = w >> 2, wn = w & 3;          // 2M x 4N waves
  const int r = lane & 15, q = lane >> 4;
  const int m0 = mt * 256;
  const unsigned short* Wrow = WB + (size_t)(ct * 256) * 768;
  const int nkt = (ct < 2) ? 12 : 8;          // K-tiles of 64

  unsigned short* const Ab0 = SM;
  unsigned short* const Ab1 = SM + 16384;
  unsigned short* const Bb0 = SM + 32768;
  unsigned short* const Bb1 = SM + 49152;

  f32x4 acc[8][4] = {};

  const int smi = t >> 3, sc = t & 7;         // staging: row-in-round, chunk

  auto ISSUE_A = [&](unsigned short* dst, int kt, int rbase) {
    int row = rbase + smi;
    int gc = sc ^ (row & 7);
    const unsigned short* ga;
    if (kt < 8) ga = AVH + (size_t)(m0 + row) * 512 + kt * 64 + gc * 8;
    else        ga = H1  + (size_t)(m0 + row) * 256 + (kt - 8) * 64 + gc * 8;
    __builtin_amdgcn_global_load_lds(GLOBAL_AS(ga), LDS_AS(&dst[row * 64 + sc * 8]), 16, 0, 0);
  };
  auto ISSUE_B = [&](unsigned short* dst, int kt, int rbase) {
    int row = rbase + smi;
    int gc = sc ^ (row & 7);
    __builtin_amdgcn_global_load_lds(GLOBAL_AS(Wrow + (size_t)row * 768 + kt * 64 + gc * 8),
                                     LDS_AS(&dst[row * 64 + sc * 8]), 16, 0, 0);
  };

  // prologue: stage tile 0 in the canonical order
  ISSUE_B(Bb0, 0, 0); ISSUE_B(Bb0, 0, 64); ISSUE_B(Bb0, 0, 128); ISSUE_B(Bb0, 0, 192);
  ISSUE_A(Ab0, 0, 0); ISSUE_A(Ab0, 0, 128); ISSUE_A(Ab0, 0, 64); ISSUE_A(Ab0, 0, 192);
  asm volatile("s_waitcnt vmcnt(2)" ::: "memory");
  __builtin_amdgcn_s_barrier();

#define PRE_PHASE(XG0, ISSUES, TAIL)                                         \
    {                                                                        \
      int ra0 = wm * 128 + (XG0) * 16 + r, ra1 = ra0 + 16;                   \
      frag a00 = *(const frag*)&A[ra0 * 64 + ((q ^ (ra0 & 7)) * 8)];         \
      frag a01 = *(const frag*)&A[ra0 * 64 + (((4 + q) ^ (ra0 & 7)) * 8)];   \
      frag a10 = *(const frag*)&A[ra1 * 64 + ((q ^ (ra1 & 7)) * 8)];         \
      frag a11 = *(const frag*)&A[ra1 * 64 + (((4 + q) ^ (ra1 & 7)) * 8)];   \
      ISSUES;                                                                \
      __builtin_amdgcn_s_setprio(1);                                         \
      _Pragma("unroll")                                                      \
      for (int y = 0; y < 4; ++y) {                                          \
        acc[(XG0)][y]     = MFMA16(a00, bf[y][0], acc[(XG0)][y], 0, 0, 0);   \
        acc[(XG0)][y]     = MFMA16(a01, bf[y][1], acc[(XG0)][y], 0, 0, 0);   \
        acc[(XG0)+1][y]   = MFMA16(a10, bf[y][0], acc[(XG0)+1][y], 0, 0, 0); \
        acc[(XG0)+1][y]   = MFMA16(a11, bf[y][1], acc[(XG0)+1][y], 0, 0, 0); \
      }                                                                      \
      __builtin_amdgcn_s_setprio(0);                                         \
      TAIL;                                                                  \
      asm volatile("" ::: "memory");                                         \
      __builtin_amdgcn_s_barrier();                                          \
    }

  for (int kt = 0; kt < nkt; ++kt) {
    unsigned short* A  = (kt & 1) ? Ab1 : Ab0;
    unsigned short* B  = (kt & 1) ? Bb1 : Bb0;
    unsigned short* An = (kt & 1) ? Ab0 : Ab1;
    unsigned short* Bn = (kt & 1) ? Bb0 : Bb1;
    const bool more = (kt + 1 < nkt);

    frag bf[4][2];
#pragma unroll
    for (int y = 0; y < 4; ++y) {
      int rb = wn * 64 + y * 16 + r;
      bf[y][0] = *(const frag*)&B[rb * 64 + ((q ^ (rb & 7)) * 8)];
      bf[y][1] = *(const frag*)&B[rb * 64 + (((4 + q) ^ (rb & 7)) * 8)];
    }

    PRE_PHASE(0,
      { if (more) { ISSUE_B(Bn, kt + 1, 0); ISSUE_B(Bn, kt + 1, 64); } },
      { })
    PRE_PHASE(2,
      { if (more) { ISSUE_B(Bn, kt + 1, 128); ISSUE_B(Bn, kt + 1, 192); } },
      { if (more) asm volatile("s_waitcnt vmcnt(4)" ::: "memory");
        else      asm volatile("s_waitcnt vmcnt(0)" ::: "memory"); })
    PRE_PHASE(4,
      { if (more) { ISSUE_A(An, kt + 1, 0); ISSUE_A(An, kt + 1, 128); } },
      { })
    PRE_PHASE(6,
      { if (more) { ISSUE_A(An, kt + 1, 64); ISSUE_A(An, kt + 1, 192); } },
      { if (more) asm volatile("s_waitcnt vmcnt(2)" ::: "memory"); })
  }
#undef PRE_PHASE

  // epilogue: acc -> L[256][256] (chunk swizzle jc^(c&31)) -> full lines
  unsigned short* L = SM;
#pragma unroll
  for (int xg = 0; xg < 8; ++xg) {
#pragma unroll
    for (int y = 0; y < 4; ++y) {
      int j = wn * 64 + y * 16 + r;
      int jc = j >> 3, jl = j & 7;
#pragma unroll
      for (int g = 0; g < 4; ++g) {
        int c = wm * 128 + xg * 16 + q * 4 + g;
        L[c * 256 + ((jc ^ (c & 31)) * 8) + jl] = f2bf(acc[xg][y][g]);
      }
    }
  }
  __syncthreads();
  if (ct == 1) {
    // fused l2 As-prep: RH = sigm(SG4 + pre4) * H1 -> PRE gate-4 slot
#pragma unroll
    for (int rr = 0; rr < 16; ++rr) {
      int unit = rr * 512 + t;
      int row = unit >> 5, ch = unit & 31;
      size_t grow = (size_t)(m0 + row);
      frag v  = *(const frag*)&L[row * 256 + ((ch ^ (row & 31)) * 8)];
      frag hh = *(const frag*)(H1 + grow * 256 + ch * 8);
      const float* sgr = SG + (size_t)(row & 127) * 768 + 256 + ch * 8;
      f32x4 s0 = *(const f32x4*)(sgr);
      f32x4 s1 = *(const f32x4*)(sgr + 4);
      frag o;
#pragma unroll
      for (int e = 0; e < 8; ++e) {
        float sv = (e < 4) ? s0[e] : s1[e - 4];
        float rv = sigm(sv + bf2f((unsigned short)v[e]));
        o[e] = (short)f2bf(rv * bf2f((unsigned short)hh[e]));
      }
      *(frag*)&PRE[grow * 768 + 256 + ch * 8] = o;
    }
  } else {
#pragma unroll
    for (int rr = 0; rr < 16; ++rr) {
      int unit = rr * 512 + t;
      int row = unit >> 5, ch = unit & 31;
      frag v = *(const frag*)&L[row * 256 + ((ch ^ (row & 31)) * 8)];
      *(frag*)&PRE[(size_t)(m0 + row) * 768 + ct * 256 + ch * 8] = v;
    }
  }
}

// ---------------------------------------------------------------------------
// Fused layer-1 (R8): single-buffer structure; epilogue-2 reuses acc so
// peak regs = ~136 arch + 64 AGPR -> 2 waves/SIMD; launch_bounds(256,2).
// ---------------------------------------------------------------------------
__global__ __launch_bounds__(256, 2) void gemm_l1(
    const float* __restrict__ XW, const float* __restrict__ SW,
    const float* __restrict__ x,
    const float* __restrict__ b3, const float* __restrict__ b4,
    const float* __restrict__ b5, const float* __restrict__ bu3,
    const float* __restrict__ bu5,
    const float* __restrict__ colsum, const float* __restrict__ rowsum,
    const unsigned short* __restrict__ u5b,
    const unsigned short* __restrict__ KTbN, const unsigned short* __restrict__ KbN,
    unsigned short* __restrict__ H1, unsigned short* __restrict__ AVH)
{
  __shared__ unsigned short SM[17408];   // As[0:4096] | Bs[4096:8192]; L = SM (epi)
  unsigned short* As = SM;
  unsigned short* Bs = SM + 4096;
  unsigned short* L  = SM;               // [128 j][136] : L[j][c] = h1[c][j]
  __shared__ float tP1[256], tP2[256], tP3[256], tX[256];
  __shared__ float tZ1[256], tZ2[256], tZ3[256];
  __shared__ float tV1[256], tV2[256], tV3[256];
  __shared__ float tCS[128], tRS[128];

  const int t = threadIdx.x, bid = blockIdx.x;
  const int xcd = bid & 7, slot = bid >> 3;
  const int n  = xcd * 128 + (slot >> 1);
  const int nt = slot & 1;
  const int lane = t & 63, w = t >> 6, wm = w >> 1, wn = w & 1;
  const int r = lane & 15, q = lane >> 4;
  const int n0 = nt * 128;
  const float* xw = XW + (size_t)n * 1792;

  {
    int i = t;
    float xwi0 = xw[i], xwi1 = xw[256 + i], xwi2 = xw[512 + i], xwi3 = xw[768 + i];
    float xwi4 = xw[1024 + i], xwi5 = xw[1280 + i], xwu = xw[1536 + i];
    tP1[i] = SW[512 + i] - xwi2;
    tP2[i] = SW[768 + i] - xwi3;
    tP3[i] = xwu + b4[i] + bu3[i];
    tX[i]  = x[(size_t)n * HID + i];
    tZ1[i] = SW[i] - xwi0;
    tZ2[i] = SW[256 + i] - xwi1;
    tZ3[i] = xwu + b3[i] + bu3[i];
    tV1[i] = SW[1024 + i] - xwi4;
    tV2[i] = SW[1280 + i] - xwi5;
    tV3[i] = b5[i] + bu5[i];
    if (t < 128) { tCS[t] = colsum[t]; tRS[t] = rowsum[t]; }
  }
  __syncthreads();

  f32x4 acc[4][4] = {};

  for (int kb = 0; kb < 256; kb += 32) {
#pragma unroll
    for (int i = 0; i < 2; ++i) {
      int u  = i * 256 + t;
      int mi = u >> 2;
      int c  = u & 3;
      int k  = kb + c * 8;
      int gc = c ^ ((mi >> 1) & 3);
      __builtin_amdgcn_global_load_lds(GLOBAL_AS(u5b + (size_t)(n0 + mi) * 256 + kb + gc * 8),
                                       LDS_AS(&Bs[u * 8]), 16, 0, 0);
      float cs = tCS[mi], rs = tRS[mi];
      frag a;
#pragma unroll
      for (int e = 0; e < 8; ++e) {
        int i2 = k + e;
        float pre = cs * tP1[i2] + rs * tP2[i2] + tP3[i2];
        a[e] = (short)f2bf(sigm(pre) * tX[i2]);
      }
      *(frag*)&As[mi * 32 + (gc * 8)] = a;
    }
    __syncthreads();

    frag af[4], bf_[4];
#pragma unroll
    for (int xx = 0; xx < 4; ++xx) {
      int ra = wm * 64 + xx * 16 + r;
      int rb = wn * 64 + xx * 16 + r;
      af[xx]  = *(const frag*)&As[ra * 32 + ((q ^ ((ra >> 1) & 3)) * 8)];
      bf_[xx] = *(const frag*)&Bs[rb * 32 + ((q ^ ((rb >> 1) & 3)) * 8)];
    }
#pragma unroll
    for (int xx = 0; xx < 4; ++xx)
#pragma unroll
      for (int y = 0; y < 4; ++y)
        acc[xx][y] = MFMA16(af[xx], bf_[y], acc[xx][y], 0, 0, 0);
    __syncthreads();
  }

  // epilogue 1: GRU update -> H1 (global) and L[j][c]=h1[c][j] (LDS)
#pragma unroll
  for (int xx = 0; xx < 4; ++xx) {
#pragma unroll
    for (int y = 0; y < 4; ++y) {
      int j = wn * 64 + y * 16 + r;        // local hidden col
      int i = n0 + j;                      // global hidden col
      frag4 pack;
#pragma unroll
      for (int g = 0; g < 4; ++g) {
        int c = wm * 64 + xx * 16 + q * 4 + g;
        float cs = tCS[c], rs = tRS[c];
        float z  = sigm(cs * tZ1[i] + rs * tZ2[i] + tZ3[i]);
        float p5 = cs * tV1[i] + rs * tV2[i] + tV3[i] + acc[xx][y][g];
        float h1 = (1.0f - z) * tX[i] + z * tanh_fast(p5);
        unsigned short hb = f2bf(h1);
        pack[g] = (short)hb;
        H1[(size_t)(n * 128 + c) * HID + i] = hb;
      }
      *(frag4*)&L[j * 136 + (wm * 64 + xx * 16 + q * 4)] = pack;
    }
  }
  __syncthreads();

  // epilogue 2: AVH_n[:, s*256 + n0 + j] = sum_c Ksrc[c',c] * h1[c][j]
  // REUSES acc (re-zeroed) so AGPR peak stays at 64.
#pragma unroll 1
  for (int s = 0; s < 2; ++s) {
    const unsigned short* Ks = s ? KbN : KTbN;
#pragma unroll
    for (int xx = 0; xx < 4; ++xx)
#pragma unroll
      for (int y = 0; y < 4; ++y)
        acc[xx][y] = (f32x4){0.0f, 0.0f, 0.0f, 0.0f};
#pragma unroll
    for (int kb = 0; kb < 4; ++kb) {
      frag af[4], bf_[4];
#pragma unroll
      for (int xx = 0; xx < 4; ++xx) {
        int cp = wm * 64 + xx * 16 + r;
        af[xx] = *(const frag*)(Ks + (size_t)cp * 128 + kb * 32 + q * 8);
        int j = wn * 64 + xx * 16 + r;
        bf_[xx] = *(const frag*)&L[j * 136 + kb * 32 + q * 8];
      }
#pragma unroll
      for (int xx = 0; xx < 4; ++xx)
#pragma unroll
        for (int y = 0; y < 4; ++y)
          acc[xx][y] = MFMA16(af[xx], bf_[y], acc[xx][y], 0, 0, 0);
    }
#pragma unroll
    for (int xx = 0; xx < 4; ++xx)
#pragma unroll
      for (int y = 0; y < 4; ++y) {
        int col = s * 256 + n0 + wn * 64 + y * 16 + r;
#pragma unroll
        for (int g = 0; g < 4; ++g) {
          int cp = wm * 64 + xx * 16 + q * 4 + g;
          AVH[(size_t)(n * 128 + cp) * 512 + col] = f2bf(acc[xx][y][g]);
        }
      }
  }
}

// ---------------------------------------------------------------------------
// Fused layer-2 (R11): 256x256 tile, 512 threads, K=256 (4 K-tiles of 64),
// same 4-phase counted-vmcnt pipeline as gemm_pre. A = RH (PRE gate-4 slot,
// precomputed by gemm_pre ct==1), B = u5b. Epilogue: two-pass f32 LDS
// transpose (L[128][256], word-XOR swizzle) -> vectorized z/pv/out.
// grid 512 = 8 xcd x 64.
// ---------------------------------------------------------------------------
__global__ __launch_bounds__(512, 2) void gemm_l2(
    const unsigned short* __restrict__ PRE, const float* __restrict__ SG,
    const unsigned short* __restrict__ H1, const unsigned short* __restrict__ u5b,
    float* __restrict__ out)
{
  __shared__ __align__(16) unsigned short SM[65536];   // 128 KiB
  const int t = threadIdx.x, bid = blockIdx.x;
  const int xcd = bid & 7, slot = bid >> 3;
  const int mt = xcd * 64 + slot;
  const int lane = t & 63, w = t >> 6;
  const int wm = w >> 2, wn = w & 3;
  const int r = lane & 15, q = lane >> 4;
  const int m0 = mt * 256;
  const int nkt = 4;

  unsigned short* const Ab0 = SM;
  unsigned short* const Ab1 = SM + 16384;
  unsigned short* const Bb0 = SM + 32768;
  unsigned short* const Bb1 = SM + 49152;

  f32x4 acc[8][4] = {};

  const int smi = t >> 3, sc = t & 7;

  auto ISSUE_A = [&](unsigned short* dst, int kt, int rbase) {
    int row = rbase + smi;
    int gc = sc ^ (row & 7);
    const unsigned short* ga = PRE + (size_t)(m0 + row) * 768 + 256 + kt * 64 + gc * 8;
    __builtin_amdgcn_global_load_lds(GLOBAL_AS(ga), LDS_AS(&dst[row * 64 + sc * 8]), 16, 0, 0);
  };
  auto ISSUE_B = [&](unsigned short* dst, int kt, int rbase) {
    int row = rbase + smi;
    int gc = sc ^ (row & 7);
    __builtin_amdgcn_global_load_lds(GLOBAL_AS(u5b + (size_t)row * 256 + kt * 64 + gc * 8),
                                     LDS_AS(&dst[row * 64 + sc * 8]), 16, 0, 0);
  };

  ISSUE_B(Bb0, 0, 0); ISSUE_B(Bb0, 0, 64); ISSUE_B(Bb0, 0, 128); ISSUE_B(Bb0, 0, 192);
  ISSUE_A(Ab0, 0, 0); ISSUE_A(Ab0, 0, 128); ISSUE_A(Ab0, 0, 64); ISSUE_A(Ab0, 0, 192);
  asm volatile("s_waitcnt vmcnt(2)" ::: "memory");
  __builtin_amdgcn_s_barrier();

#define L2_PHASE(XG0, ISSUES, TAIL)                                          \
    {                                                                        \
      int ra0 = wm * 128 + (XG0) * 16 + r, ra1 = ra0 + 16;                   \
      frag a00 = *(const frag*)&A[ra0 * 64 + ((q ^ (ra0 & 7)) * 8)];         \
      frag a01 = *(const frag*)&A[ra0 * 64 + (((4 + q) ^ (ra0 & 7)) * 8)];   \
      frag a10 = *(const frag*)&A[ra1 * 64 + ((q ^ (ra1 & 7)) * 8)];         \
      frag a11 = *(const frag*)&A[ra1 * 64 + (((4 + q) ^ (ra1 & 7)) * 8)];   \
      ISSUES;                                                                \
      __builtin_amdgcn_s_setprio(1);                                         \
      _Pragma("unroll")                                                      \
      for (int y = 0; y < 4; ++y) {                                          \
        acc[(XG0)][y]     = MFMA16(a00, bf[y][0], acc[(XG0)][y], 0, 0, 0);   \
        acc[(XG0)][y]     = MFMA16(a01, bf[y][1], acc[(XG0)][y], 0, 0, 0);   \
        acc[(XG0)+1][y]   = MFMA16(a10, bf[y][0], acc[(XG0)+1][y], 0, 0, 0); \
        acc[(XG0)+1][y]   = MFMA16(a11, bf[y][1], acc[(XG0)+1][y], 0, 0, 0); \
      }                                                                      \
      __builtin_amdgcn_s_setprio(0);                                         \
      TAIL;                                                                  \
      asm volatile("" ::: "memory");                                         \
      __builtin_amdgcn_s_barrier();                                          \
    }

  for (int kt = 0; kt < nkt; ++kt) {
    unsigned short* A  = (kt & 1) ? Ab1 : Ab0;
    unsigned short* B  = (kt & 1) ? Bb1 : Bb0;
    unsigned short* An = (kt & 1) ? Ab0 : Ab1;
    unsigned short* Bn = (kt & 1) ? Bb0 : Bb1;
    const bool more = (kt + 1 < nkt);

    frag bf[4][2];
#pragma unroll
    for (int y = 0; y < 4; ++y) {
      int rb = wn * 64 + y * 16 + r;
      bf[y][0] = *(const frag*)&B[rb * 64 + ((q ^ (rb & 7)) * 8)];
      bf[y][1] = *(const frag*)&B[rb * 64 + (((4 + q) ^ (rb & 7)) * 8)];
    }

    L2_PHASE(0,
      { if (more) { ISSUE_B(Bn, kt + 1, 0); ISSUE_B(Bn, kt + 1, 64); } },
      { })
    L2_PHASE(2,
      { if (more) { ISSUE_B(Bn, kt + 1, 128); ISSUE_B(Bn, kt + 1, 192); } },
      { if (more) asm volatile("s_waitcnt vmcnt(4)" ::: "memory");
        else      asm volatile("s_waitcnt vmcnt(0)" ::: "memory"); })
    L2_PHASE(4,
      { if (more) { ISSUE_A(An, kt + 1, 0); ISSUE_A(An, kt + 1, 128); } },
      { })
    L2_PHASE(6,
      { if (more) { ISSUE_A(An, kt + 1, 64); ISSUE_A(An, kt + 1, 192); } },
      { if (more) asm volatile("s_waitcnt vmcnt(2)" ::: "memory"); })
  }
#undef L2_PHASE

  // ---- epilogue: two-pass f32 transpose (L[128][256], word-XOR swizzle) ----
  float* L = (float*)SM;
#pragma unroll 1
  for (int p = 0; p < 2; ++p) {
    if (p) __syncthreads();                  // pass-0 reads done before overwrite
    if (wm == p) {
#pragma unroll
      for (int xg = 0; xg < 8; ++xg)
#pragma unroll
        for (int y = 0; y < 4; ++y) {
          int j = wn * 64 + y * 16 + r;
#pragma unroll
          for (int g = 0; g < 4; ++g) {
            int lr = xg * 16 + q * 4 + g;    // 0..127
            L[lr * 256 + (j ^ ((lr & 7) << 2))] = acc[xg][y][g];
          }
        }
    }
    __syncthreads();
#pragma unroll
    for (int rr = 0; rr < 8; ++rr) {
      int unit = rr * 512 + t;
      int row = unit >> 5, ch = unit & 31;   // row 0..127, ch 0..31
      size_t grow = (size_t)(m0 + p * 128 + row);
      int c = (int)(grow & 127);
      int j0 = ch * 8;
      const int off = (row & 7) << 2;
      f32x4 a0 = *(const f32x4*)&L[row * 256 + (j0 ^ off)];
      f32x4 a1 = *(const f32x4*)&L[row * 256 + ((j0 + 4) ^ off)];
      const unsigned short* prow = PRE + grow * 768;
      frag pz = *(const frag*)(prow + j0);
      frag pp = *(const frag*)(prow + 512 + j0);
      frag hh = *(const frag*)(H1 + grow * 256 + j0);
      const float* sgr = SG + (size_t)c * 768;
      f32x4 sz0 = *(const f32x4*)(sgr + j0);
      f32x4 sz1 = *(const f32x4*)(sgr + j0 + 4);
      f32x4 sp0 = *(const f32x4*)(sgr + 512 + j0);
      f32x4 sp1 = *(const f32x4*)(sgr + 512 + j0 + 4);
      f32x4 o0, o1;
#pragma unroll
      for (int e = 0; e < 8; ++e) {
        float sz = (e < 4) ? sz0[e] : sz1[e - 4];
        float sp = (e < 4) ? sp0[e] : sp1[e - 4];
        float av = (e < 4) ? a0[e] : a1[e - 4];
        float z  = sigm(sz + bf2f((unsigned short)pz[e]));
        float pv = sp + bf2f((unsigned short)pp[e]) + av;
        float h  = bf2f((unsigned short)hh[e]);
        float o  = (1.0f - z) * h + z * tanh_fast(pv);
        if (e < 4) o0[e] = o; else o1[e - 4] = o;
      }
      *(f32x4*)&out[grow * 256 + j0] = o0;
      *(f32x4*)&out[grow * 256 + j0 + 4] = o1;
    }
  }
}

// ---------------------------------------------------------------------------
// prep kernels
// ---------------------------------------------------------------------------
__global__ __launch_bounds__(256) void prep_cast(
    const float* __restrict__ x, const float* __restrict__ Kn,
    const float* __restrict__ w3, const float* __restrict__ u3,
    const float* __restrict__ w4, const float* __restrict__ w5,
    const float* __restrict__ u5,
    unsigned short* __restrict__ xb, unsigned short* __restrict__ WB,
    unsigned short* __restrict__ WB2, unsigned short* __restrict__ u5b,
    unsigned short* __restrict__ KbN, unsigned short* __restrict__ KTbN)
{
  int idx = blockIdx.x * 256 + threadIdx.x;
  if (idx < 262144) { xb[idx] = f2bf(x[idx]); return; }
  idx -= 262144;
  if (idx < 589824) {
    int col = idx / 768, j = idx % 768;
    int g = col >> 8, i = col & 255;
    float v;
    if (j < 512) { const float* wg = (g == 0) ? w3 : (g == 1) ? w4 : w5; v = wg[(size_t)i * 512 + j]; }
    else v = (g < 2) ? u3[(size_t)i * 256 + (j - 512)] : 0.0f;
    WB[(size_t)col * 768 + j] = f2bf(v);
    return;
  }
  idx -= 589824;
  if (idx < 458752) {
    int col = idx / 256, h = idx % 256;
    int b = col >> 8, i = col & 255;
    float v = (b < 6) ? ((b < 2 ? w3 : (b < 4 ? w4 : w5))[(size_t)i * 512 + (b & 1) * 256 + h])
                      : u3[(size_t)i * 256 + h];
    WB2[(size_t)col * 256 + h] = f2bf(v);
    return;
  }
  idx -= 458752;
  if (idx < 65536) { u5b[idx] = f2bf(u5[idx]); return; }
  idx -= 65536;
  if (idx < 16384) { int c = idx >> 7, k = idx & 127; KbN[idx]  = f2bf(-Kn[c * 128 + k]); return; }
  idx -= 16384;
  { int c = idx >> 7, k = idx & 127; KTbN[idx] = f2bf(-Kn[k * 128 + c]); }
}

__global__ __launch_bounds__(256) void prep_reduce(
    const float* __restrict__ x, const float* __restrict__ Kn,
    float* __restrict__ S, float* __restrict__ colsum, float* __restrict__ rowsum)
{
  int b = blockIdx.x, t = threadIdx.x;
  if (b < 8) {
    float s = 0.f;
    for (int n = 0; n < 128; ++n) s += x[(size_t)(b * 128 + n) * HID + t];
    atomicAdd(&S[t], s);
  } else if (b == 8) {
    if (t < NCLS) { float s = 0.f; for (int k = 0; k < NCLS; ++k) s += Kn[k * NCLS + t]; colsum[t] = s; }
  } else {
    if (t < NCLS) { float s = 0.f; for (int k = 0; k < NCLS; ++k) s += Kn[t * NCLS + k]; rowsum[t] = s; }
  }
}

__global__ __launch_bounds__(256) void prep_sw(
    const float* __restrict__ S, const float* __restrict__ w3,
    const float* __restrict__ w4, const float* __restrict__ w5, float* __restrict__ SW)
{
  int col = blockIdx.x * 256 + threadIdx.x;
  int b = col >> 8, i = col & 255;
  const float* w = (b < 2) ? w3 : (b < 4) ? w4 : w5;
  const float* row = w + (size_t)i * 512 + (b & 1) * 256;
  float s = 0.f;
  for (int h = 0; h < HID; ++h) s += S[h] * row[h];
  SW[col] = s;
}

__global__ __launch_bounds__(256) void reduce_hs(
    const unsigned short* __restrict__ H1, float* __restrict__ hs)
{
  int bid = blockIdx.x;
  int c = bid >> 5, nch = bid & 31;
  int i = threadIdx.x;
  const unsigned short* p = H1 + (size_t)nch * 32 * NCLS * HID + (size_t)c * HID + i;
  float s = 0.f;
  for (int n = 0; n < 32; ++n) s += bf2f(p[(size_t)n * NCLS * HID]);
  atomicAdd(&hs[c * HID + i], s);
}

__global__ __launch_bounds__(256) void p2a(
    const float* __restrict__ hs, const float* __restrict__ w3,
    const float* __restrict__ w4, const float* __restrict__ w5, float* __restrict__ hsW)
{
  __shared__ float hrow[HID];
  int k = blockIdx.x & 127, b = blockIdx.x >> 7;
  int t = threadIdx.x;
  hrow[t] = hs[k * HID + t];
  __syncthreads();
  const float* w = (b < 2) ? w3 : (b < 4) ? w4 : w5;
  const float* row = w + (size_t)t * 512 + (b & 1) * 256;
  float s = 0.f;
  for (int h = 0; h < HID; ++h) s += hrow[h] * row[h];
  hsW[(size_t)k * 1536 + b * 256 + t] = s;
}

__global__ __launch_bounds__(256) void p2b(
    const float* __restrict__ hsW, const float* __restrict__ Kn,
    const float* __restrict__ b3, const float* __restrict__ b4, const float* __restrict__ b5,
    const float* __restrict__ bu3, const float* __restrict__ bu5, float* __restrict__ SG)
{
  __shared__ float kc[NCLS], kr[NCLS];
  int c = blockIdx.x, t = threadIdx.x;
  if (t < NCLS) { kc[t] = Kn[t * NCLS + c]; kr[t] = Kn[c * NCLS + t]; }
  __syncthreads();
  for (int g = 0; g < 3; ++g) {
    int i = t;
    const float* L = hsW + (size_t)(2 * g) * 256 + i;
    const float* R = hsW + (size_t)(2 * g + 1) * 256 + i;
    float s = 0.f;
    for (int k = 0; k < NCLS; ++k) s += kc[k] * L[(size_t)k * 1536] + kr[k] * R[(size_t)k * 1536];
    const float* bg = (g == 0) ? b3 : (g == 1) ? b4 : b5;
    s += bg[i] + ((g < 2) ? bu3[i] : bu5[i]);
    SG[(size_t)c * 768 + g * 256 + i] = s;
  }
}

// ---------------------------------------------------------------------------
extern "C" void kernel_launch(void* const* d_in, const int* in_sizes, int n_in,
                              void* d_out, int out_size, void* d_ws, size_t ws_size,
                              hipStream_t stream) {
  (void)in_sizes; (void)n_in; (void)out_size; (void)ws_size;
  const float* x   = (const float*)d_in[0];
  const float* Kn  = (const float*)d_in[1];
  const float* w3  = (const float*)d_in[2];
  const float* b3  = (const float*)d_in[3];
  const float* u3  = (const float*)d_in[4];
  const float* bu3 = (const float*)d_in[5];
  const float* w4  = (const float*)d_in[6];
  const float* b4  = (const float*)d_in[7];
  const float* w5  = (const float*)d_in[8];
  const float* b5  = (const float*)d_in[9];
  const float* u5  = (const float*)d_in[10];
  const float* bu5 = (const float*)d_in[11];
  float* out = (float*)d_out;

  char* w = (char*)d_ws;
  unsigned short* AVH = (unsigned short*)(w);                 // 131072x512 bf16 (128 MiB)
  unsigned short* PRE = (unsigned short*)(w + 134217728);     // 131072x768 bf16 (192 MiB)
  unsigned short* H1  = (unsigned short*)(w + 335544320);     // 64 MiB
  float*          XW  = (float*)(w + 402653184);              // 1024x1792 fp32
  char* misc = w + 409993216;
  float* S      = (float*)(misc);
  float* hs     = (float*)(misc + 1024);
  float* SW     = (float*)(misc + 132096);
  float* colsum = (float*)(misc + 138240);
  float* rowsum = (float*)(misc + 138752);
  float* hsW    = (float*)(misc + 139264);
  float* SG     = (float*)(misc + 925696);
  unsigned short* WB   = (unsigned short*)(misc + 1318912);
  unsigned short* WB2  = (unsigned short*)(misc + 2498560);
  unsigned short* u5b  = (unsigned short*)(misc + 3416064);
  unsigned short* KbN  = (unsigned short*)(misc + 3547136);
  unsigned short* KTbN = (unsigned short*)(misc + 3579904);
  unsigned short* xb   = (unsigned short*)(misc + 3612672);

  hipMemsetAsync(misc, 0, 132096, stream);  // S + hs

  prep_cast<<<5504, 256, 0, stream>>>(x, Kn, w3, u3, w4, w5, u5, xb, WB, WB2, u5b, KbN, KTbN);
  prep_reduce<<<10, 256, 0, stream>>>(x, Kn, S, colsum, rowsum);
  prep_sw<<<6, 256, 0, stream>>>(S, w3, w4, w5, SW);

  // XW = x @ Wcat^T  [1024,256]x[256,1792] -> fp32
  gemm_bf16<0><<<8 * 14, 256, 0, stream>>>(xb, 256, 256, xb, 256, WB2, 256, 0L,
                                           (void*)XW, 1792, 14, 256, 0xFFFFFFFFu, 8);
  // fused layer 1 -> H1 and AVH (mini-GEMMs in epilogue)
  gemm_l1<<<2048, 256, 0, stream>>>(XW, SW, x, b3, b4, b5, bu3, bu5,
                                    colsum, rowsum, u5b, KTbN, KbN, H1, AVH);

  reduce_hs<<<4096, 256, 0, stream>>>(H1, hs);
  p2a<<<768, 256, 0, stream>>>(hs, w3, w4, w5, hsW);
  p2b<<<128, 256, 0, stream>>>(hsW, Kn, b3, b4, b5, bu3, bu5, SG);

  // PRE: 256x256-tile 4-phase pipelined kernel; ct==1 writes RH (fused l2 prep)
  gemm_pre<<<1536, 512, 0, stream>>>(AVH, H1, WB, SG, PRE);

  // fused layer 2 -> out (pipelined GEMM on RH + vectorized epilogue)
  gemm_l2<<<512, 512, 0, stream>>>(PRE, SG, H1, u5b, out);
}

// Round 8
// 686.250 us; speedup vs baseline: 1.2280x; 1.2280x over previous
//
#include <hip/hip_runtime.h>
#include <cstdint>
#include <cstddef>

// ---------------------------------------------------------------------------
// Graph_8564164788735: 2-layer class-conditioned GRU-ish propagation.
// N=1024 nodes, C=128 classes, H=256. Output fp32 [N,C,H].
//
// R13: l2 hardened. R12's only unverified element was the manual
// counted-vmcnt dbuf in l2 (stale-LDS race class if the compiler reorders
// gload_lds around inline-asm waits). l2 now uses the PROVEN gemm_bf16
// loop structure: single-buffer, pure global_load_lds staging of RH
// (PRE gate-4, precomputed by gemm_pre ct==1) + u5b, __syncthreads()
// discipline (compiler-inserted full drains), then the R10-verified
// two-pass f32 LDS-transpose vectorized epilogue. The R12 win (no VALU
// As-prep in l2's loop) is preserved. gemm_pre keeps the R11-verified
// RH fusion; gemm_l1 keeps R8.
// ---------------------------------------------------------------------------

#define NODES 1024
#define NCLS  128
#define HID   256

using frag  = __attribute__((ext_vector_type(8))) short;
using frag4 = __attribute__((ext_vector_type(4))) short;
using f32x4 = __attribute__((ext_vector_type(4))) float;

__device__ __forceinline__ float bf2f(unsigned short h){
  unsigned int u = ((unsigned int)h) << 16;
  float f; __builtin_memcpy(&f, &u, 4); return f;
}
__device__ __forceinline__ unsigned short f2bf(float f){
  unsigned int u; __builtin_memcpy(&u, &f, 4);
  u = (u + 0x7fffu + ((u >> 16) & 1u)) >> 16;   // RNE
  return (unsigned short)u;
}
__device__ __forceinline__ float sigm(float x){ return 1.0f/(1.0f + __expf(-x)); }
__device__ __forceinline__ float tanh_fast(float x){ return 1.0f - 2.0f/(__expf(2.0f*x) + 1.0f); }

#define GLOBAL_AS(p) ((const __attribute__((address_space(1))) void*)(p))
#define LDS_AS(p)    ((__attribute__((address_space(3))) void*)(p))
#define MFMA16 __builtin_amdgcn_mfma_f32_16x16x32_bf16

// ---------------------------------------------------------------------------
// Generic bf16 MFMA GEMM (only used for XW). 128x128 tile, BK=32.
// ---------------------------------------------------------------------------
template<int OUT_BF16>
__global__ __launch_bounds__(256) void gemm_bf16(
    const unsigned short* __restrict__ A0, int ldA0, int K0,
    const unsigned short* __restrict__ A1, int ldA1,
    const unsigned short* __restrict__ BT, int ldB, long bStride,
    void* __restrict__ Cptr, int ldC,
    int Ntiles, int Ktot, unsigned int aMask, int Mtiles)
{
  __shared__ unsigned short As[4096];
  __shared__ unsigned short Bs[4096];
  const int t   = threadIdx.x;
  const int bid = blockIdx.x;
  const int xcd = bid & 7, slot = bid >> 3;
  const int mtPerX = (Mtiles >= 8) ? (Mtiles >> 3) : 1;
  const int mt = xcd * mtPerX + slot / Ntiles;
  const int nt = slot % Ntiles;
  const int lane = t & 63, w = t >> 6;
  const int wm = w >> 1, wn = w & 1;
  const int r = lane & 15, q = lane >> 4;
  const int m0 = mt * 128, n0 = nt * 128;
  const unsigned short* Bbase = BT + (size_t)mt * (size_t)bStride;

  f32x4 acc[4][4] = {};

  for (int kb = 0; kb < Ktot; kb += 32) {
#pragma unroll
    for (int i = 0; i < 2; ++i) {
      int u  = i * 256 + t;
      int mi = u >> 2;
      int kc = (u & 3) * 8;
      int k  = kb + kc;
      const unsigned short* ga;
      if (k < K0) ga = A0 + (size_t)((unsigned int)(m0 + mi) & aMask) * (size_t)ldA0 + k;
      else        ga = A1 + (size_t)(m0 + mi) * (size_t)ldA1 + (k - K0);
      __builtin_amdgcn_global_load_lds(GLOBAL_AS(ga), LDS_AS(&As[u * 8]), 16, 0, 0);
      const unsigned short* gb = Bbase + (size_t)(n0 + mi) * (size_t)ldB + k;
      __builtin_amdgcn_global_load_lds(GLOBAL_AS(gb), LDS_AS(&Bs[u * 8]), 16, 0, 0);
    }
    __syncthreads();

    frag af[4], bf_[4];
#pragma unroll
    for (int x = 0; x < 4; ++x) {
      af[x]  = *(const frag*)&As[(wm * 64 + x * 16 + r) * 32 + q * 8];
      bf_[x] = *(const frag*)&Bs[(wn * 64 + x * 16 + r) * 32 + q * 8];
    }
#pragma unroll
    for (int x = 0; x < 4; ++x)
#pragma unroll
      for (int y = 0; y < 4; ++y)
        acc[x][y] = MFMA16(af[x], bf_[y], acc[x][y], 0, 0, 0);
    __syncthreads();
  }

#pragma unroll
  for (int x = 0; x < 4; ++x) {
#pragma unroll
    for (int y = 0; y < 4; ++y) {
      int col = n0 + wn * 64 + y * 16 + r;
#pragma unroll
      for (int g = 0; g < 4; ++g) {
        long row = m0 + wm * 64 + x * 16 + q * 4 + g;
        if (OUT_BF16) ((unsigned short*)Cptr)[row * (long)ldC + col] = f2bf(acc[x][y][g]);
        else          ((float*)Cptr)[row * (long)ldC + col] = acc[x][y][g];
      }
    }
  }
}

// ---------------------------------------------------------------------------
// gemm_pre (R11): R9 4-phase pipeline; ct==1 epilogue fuses l2's As-prep:
// RH = sigm(SG4 + pre4) * H1, written into PRE's gate-4 slot.
// ---------------------------------------------------------------------------
__global__ __launch_bounds__(512, 2) void gemm_pre(
    const unsigned short* __restrict__ AVH, const unsigned short* __restrict__ H1,
    const unsigned short* __restrict__ WB, const float* __restrict__ SG,
    unsigned short* __restrict__ PRE)
{
  __shared__ __align__(16) unsigned short SM[65536];   // 128 KiB
  const int t   = threadIdx.x;
  const int bid = blockIdx.x;
  const int xcd = bid & 7, slot = bid >> 3;
  const int mt = xcd * 64 + slot / 3;
  const int ct = slot % 3;
  const int lane = t & 63, w = t >> 6;
  const int wm = w >> 2, wn = w & 3;          // 2M x 4N waves
  const int r = lane & 15, q = lane >> 4;
  const int m0 = mt * 256;
  const unsigned short* Wrow = WB + (size_t)(ct * 256) * 768;
  const int nkt = (ct < 2) ? 12 : 8;          // K-tiles of 64

  unsigned short* const Ab0 = SM;
  unsigned short* const Ab1 = SM + 16384;
  unsigned short* const Bb0 = SM + 32768;
  unsigned short* const Bb1 = SM + 49152;

  f32x4 acc[8][4] = {};

  const int smi = t >> 3, sc = t & 7;         // staging: row-in-round, chunk

  auto ISSUE_A = [&](unsigned short* dst, int kt, int rbase) {
    int row = rbase + smi;
    int gc = sc ^ (row & 7);
    const unsigned short* ga;
    if (kt < 8) ga = AVH + (size_t)(m0 + row) * 512 + kt * 64 + gc * 8;
    else        ga = H1  + (size_t)(m0 + row) * 256 + (kt - 8) * 64 + gc * 8;
    __builtin_amdgcn_global_load_lds(GLOBAL_AS(ga), LDS_AS(&dst[row * 64 + sc * 8]), 16, 0, 0);
  };
  auto ISSUE_B = [&](unsigned short* dst, int kt, int rbase) {
    int row = rbase + smi;
    int gc = sc ^ (row & 7);
    __builtin_amdgcn_global_load_lds(GLOBAL_AS(Wrow + (size_t)row * 768 + kt * 64 + gc * 8),
                                     LDS_AS(&dst[row * 64 + sc * 8]), 16, 0, 0);
  };

  // prologue: stage tile 0 in the canonical order
  ISSUE_B(Bb0, 0, 0); ISSUE_B(Bb0, 0, 64); ISSUE_B(Bb0, 0, 128); ISSUE_B(Bb0, 0, 192);
  ISSUE_A(Ab0, 0, 0); ISSUE_A(Ab0, 0, 128); ISSUE_A(Ab0, 0, 64); ISSUE_A(Ab0, 0, 192);
  asm volatile("s_waitcnt vmcnt(2)" ::: "memory");
  __builtin_amdgcn_s_barrier();

#define PRE_PHASE(XG0, ISSUES, TAIL)                                         \
    {                                                                        \
      int ra0 = wm * 128 + (XG0) * 16 + r, ra1 = ra0 + 16;                   \
      frag a00 = *(const frag*)&A[ra0 * 64 + ((q ^ (ra0 & 7)) * 8)];         \
      frag a01 = *(const frag*)&A[ra0 * 64 + (((4 + q) ^ (ra0 & 7)) * 8)];   \
      frag a10 = *(const frag*)&A[ra1 * 64 + ((q ^ (ra1 & 7)) * 8)];         \
      frag a11 = *(const frag*)&A[ra1 * 64 + (((4 + q) ^ (ra1 & 7)) * 8)];   \
      ISSUES;                                                                \
      __builtin_amdgcn_s_setprio(1);                                         \
      _Pragma("unroll")                                                      \
      for (int y = 0; y < 4; ++y) {                                          \
        acc[(XG0)][y]     = MFMA16(a00, bf[y][0], acc[(XG0)][y], 0, 0, 0);   \
        acc[(XG0)][y]     = MFMA16(a01, bf[y][1], acc[(XG0)][y], 0, 0, 0);   \
        acc[(XG0)+1][y]   = MFMA16(a10, bf[y][0], acc[(XG0)+1][y], 0, 0, 0); \
        acc[(XG0)+1][y]   = MFMA16(a11, bf[y][1], acc[(XG0)+1][y], 0, 0, 0); \
      }                                                                      \
      __builtin_amdgcn_s_setprio(0);                                         \
      TAIL;                                                                  \
      asm volatile("" ::: "memory");                                         \
      __builtin_amdgcn_s_barrier();                                          \
    }

  for (int kt = 0; kt < nkt; ++kt) {
    unsigned short* A  = (kt & 1) ? Ab1 : Ab0;
    unsigned short* B  = (kt & 1) ? Bb1 : Bb0;
    unsigned short* An = (kt & 1) ? Ab0 : Ab1;
    unsigned short* Bn = (kt & 1) ? Bb0 : Bb1;
    const bool more = (kt + 1 < nkt);

    frag bf[4][2];
#pragma unroll
    for (int y = 0; y < 4; ++y) {
      int rb = wn * 64 + y * 16 + r;
      bf[y][0] = *(const frag*)&B[rb * 64 + ((q ^ (rb & 7)) * 8)];
      bf[y][1] = *(const frag*)&B[rb * 64 + (((4 + q) ^ (rb & 7)) * 8)];
    }

    PRE_PHASE(0,
      { if (more) { ISSUE_B(Bn, kt + 1, 0); ISSUE_B(Bn, kt + 1, 64); } },
      { })
    PRE_PHASE(2,
      { if (more) { ISSUE_B(Bn, kt + 1, 128); ISSUE_B(Bn, kt + 1, 192); } },
      { if (more) asm volatile("s_waitcnt vmcnt(4)" ::: "memory");
        else      asm volatile("s_waitcnt vmcnt(0)" ::: "memory"); })
    PRE_PHASE(4,
      { if (more) { ISSUE_A(An, kt + 1, 0); ISSUE_A(An, kt + 1, 128); } },
      { })
    PRE_PHASE(6,
      { if (more) { ISSUE_A(An, kt + 1, 64); ISSUE_A(An, kt + 1, 192); } },
      { if (more) asm volatile("s_waitcnt vmcnt(2)" ::: "memory"); })
  }
#undef PRE_PHASE

  // epilogue: acc -> L[256][256] (chunk swizzle jc^(c&31)) -> full lines
  unsigned short* L = SM;
#pragma unroll
  for (int xg = 0; xg < 8; ++xg) {
#pragma unroll
    for (int y = 0; y < 4; ++y) {
      int j = wn * 64 + y * 16 + r;
      int jc = j >> 3, jl = j & 7;
#pragma unroll
      for (int g = 0; g < 4; ++g) {
        int c = wm * 128 + xg * 16 + q * 4 + g;
        L[c * 256 + ((jc ^ (c & 31)) * 8) + jl] = f2bf(acc[xg][y][g]);
      }
    }
  }
  __syncthreads();
  if (ct == 1) {
    // fused l2 As-prep: RH = sigm(SG4 + pre4) * H1 -> PRE gate-4 slot
#pragma unroll
    for (int rr = 0; rr < 16; ++rr) {
      int unit = rr * 512 + t;
      int row = unit >> 5, ch = unit & 31;
      size_t grow = (size_t)(m0 + row);
      frag v  = *(const frag*)&L[row * 256 + ((ch ^ (row & 31)) * 8)];
      frag hh = *(const frag*)(H1 + grow * 256 + ch * 8);
      const float* sgr = SG + (size_t)(row & 127) * 768 + 256 + ch * 8;
      f32x4 s0 = *(const f32x4*)(sgr);
      f32x4 s1 = *(const f32x4*)(sgr + 4);
      frag o;
#pragma unroll
      for (int e = 0; e < 8; ++e) {
        float sv = (e < 4) ? s0[e] : s1[e - 4];
        float rv = sigm(sv + bf2f((unsigned short)v[e]));
        o[e] = (short)f2bf(rv * bf2f((unsigned short)hh[e]));
      }
      *(frag*)&PRE[grow * 768 + 256 + ch * 8] = o;
    }
  } else {
#pragma unroll
    for (int rr = 0; rr < 16; ++rr) {
      int unit = rr * 512 + t;
      int row = unit >> 5, ch = unit & 31;
      frag v = *(const frag*)&L[row * 256 + ((ch ^ (row & 31)) * 8)];
      *(frag*)&PRE[(size_t)(m0 + row) * 768 + ct * 256 + ch * 8] = v;
    }
  }
}

// ---------------------------------------------------------------------------
// Fused layer-1 (R8): single-buffer structure; epilogue-2 reuses acc so
// peak regs = ~136 arch + 64 AGPR -> 2 waves/SIMD; launch_bounds(256,2).
// ---------------------------------------------------------------------------
__global__ __launch_bounds__(256, 2) void gemm_l1(
    const float* __restrict__ XW, const float* __restrict__ SW,
    const float* __restrict__ x,
    const float* __restrict__ b3, const float* __restrict__ b4,
    const float* __restrict__ b5, const float* __restrict__ bu3,
    const float* __restrict__ bu5,
    const float* __restrict__ colsum, const float* __restrict__ rowsum,
    const unsigned short* __restrict__ u5b,
    const unsigned short* __restrict__ KTbN, const unsigned short* __restrict__ KbN,
    unsigned short* __restrict__ H1, unsigned short* __restrict__ AVH)
{
  __shared__ unsigned short SM[17408];   // As[0:4096] | Bs[4096:8192]; L = SM (epi)
  unsigned short* As = SM;
  unsigned short* Bs = SM + 4096;
  unsigned short* L  = SM;               // [128 j][136] : L[j][c] = h1[c][j]
  __shared__ float tP1[256], tP2[256], tP3[256], tX[256];
  __shared__ float tZ1[256], tZ2[256], tZ3[256];
  __shared__ float tV1[256], tV2[256], tV3[256];
  __shared__ float tCS[128], tRS[128];

  const int t = threadIdx.x, bid = blockIdx.x;
  const int xcd = bid & 7, slot = bid >> 3;
  const int n  = xcd * 128 + (slot >> 1);
  const int nt = slot & 1;
  const int lane = t & 63, w = t >> 6, wm = w >> 1, wn = w & 1;
  const int r = lane & 15, q = lane >> 4;
  const int n0 = nt * 128;
  const float* xw = XW + (size_t)n * 1792;

  {
    int i = t;
    float xwi0 = xw[i], xwi1 = xw[256 + i], xwi2 = xw[512 + i], xwi3 = xw[768 + i];
    float xwi4 = xw[1024 + i], xwi5 = xw[1280 + i], xwu = xw[1536 + i];
    tP1[i] = SW[512 + i] - xwi2;
    tP2[i] = SW[768 + i] - xwi3;
    tP3[i] = xwu + b4[i] + bu3[i];
    tX[i]  = x[(size_t)n * HID + i];
    tZ1[i] = SW[i] - xwi0;
    tZ2[i] = SW[256 + i] - xwi1;
    tZ3[i] = xwu + b3[i] + bu3[i];
    tV1[i] = SW[1024 + i] - xwi4;
    tV2[i] = SW[1280 + i] - xwi5;
    tV3[i] = b5[i] + bu5[i];
    if (t < 128) { tCS[t] = colsum[t]; tRS[t] = rowsum[t]; }
  }
  __syncthreads();

  f32x4 acc[4][4] = {};

  for (int kb = 0; kb < 256; kb += 32) {
#pragma unroll
    for (int i = 0; i < 2; ++i) {
      int u  = i * 256 + t;
      int mi = u >> 2;
      int c  = u & 3;
      int k  = kb + c * 8;
      int gc = c ^ ((mi >> 1) & 3);
      __builtin_amdgcn_global_load_lds(GLOBAL_AS(u5b + (size_t)(n0 + mi) * 256 + kb + gc * 8),
                                       LDS_AS(&Bs[u * 8]), 16, 0, 0);
      float cs = tCS[mi], rs = tRS[mi];
      frag a;
#pragma unroll
      for (int e = 0; e < 8; ++e) {
        int i2 = k + e;
        float pre = cs * tP1[i2] + rs * tP2[i2] + tP3[i2];
        a[e] = (short)f2bf(sigm(pre) * tX[i2]);
      }
      *(frag*)&As[mi * 32 + (gc * 8)] = a;
    }
    __syncthreads();

    frag af[4], bf_[4];
#pragma unroll
    for (int xx = 0; xx < 4; ++xx) {
      int ra = wm * 64 + xx * 16 + r;
      int rb = wn * 64 + xx * 16 + r;
      af[xx]  = *(const frag*)&As[ra * 32 + ((q ^ ((ra >> 1) & 3)) * 8)];
      bf_[xx] = *(const frag*)&Bs[rb * 32 + ((q ^ ((rb >> 1) & 3)) * 8)];
    }
#pragma unroll
    for (int xx = 0; xx < 4; ++xx)
#pragma unroll
      for (int y = 0; y < 4; ++y)
        acc[xx][y] = MFMA16(af[xx], bf_[y], acc[xx][y], 0, 0, 0);
    __syncthreads();
  }

  // epilogue 1: GRU update -> H1 (global) and L[j][c]=h1[c][j] (LDS)
#pragma unroll
  for (int xx = 0; xx < 4; ++xx) {
#pragma unroll
    for (int y = 0; y < 4; ++y) {
      int j = wn * 64 + y * 16 + r;        // local hidden col
      int i = n0 + j;                      // global hidden col
      frag4 pack;
#pragma unroll
      for (int g = 0; g < 4; ++g) {
        int c = wm * 64 + xx * 16 + q * 4 + g;
        float cs = tCS[c], rs = tRS[c];
        float z  = sigm(cs * tZ1[i] + rs * tZ2[i] + tZ3[i]);
        float p5 = cs * tV1[i] + rs * tV2[i] + tV3[i] + acc[xx][y][g];
        float h1 = (1.0f - z) * tX[i] + z * tanh_fast(p5);
        unsigned short hb = f2bf(h1);
        pack[g] = (short)hb;
        H1[(size_t)(n * 128 + c) * HID + i] = hb;
      }
      *(frag4*)&L[j * 136 + (wm * 64 + xx * 16 + q * 4)] = pack;
    }
  }
  __syncthreads();

  // epilogue 2: AVH_n[:, s*256 + n0 + j] = sum_c Ksrc[c',c] * h1[c][j]
  // REUSES acc (re-zeroed) so AGPR peak stays at 64.
#pragma unroll 1
  for (int s = 0; s < 2; ++s) {
    const unsigned short* Ks = s ? KbN : KTbN;
#pragma unroll
    for (int xx = 0; xx < 4; ++xx)
#pragma unroll
      for (int y = 0; y < 4; ++y)
        acc[xx][y] = (f32x4){0.0f, 0.0f, 0.0f, 0.0f};
#pragma unroll
    for (int kb = 0; kb < 4; ++kb) {
      frag af[4], bf_[4];
#pragma unroll
      for (int xx = 0; xx < 4; ++xx) {
        int cp = wm * 64 + xx * 16 + r;
        af[xx] = *(const frag*)(Ks + (size_t)cp * 128 + kb * 32 + q * 8);
        int j = wn * 64 + xx * 16 + r;
        bf_[xx] = *(const frag*)&L[j * 136 + kb * 32 + q * 8];
      }
#pragma unroll
      for (int xx = 0; xx < 4; ++xx)
#pragma unroll
        for (int y = 0; y < 4; ++y)
          acc[xx][y] = MFMA16(af[xx], bf_[y], acc[xx][y], 0, 0, 0);
    }
#pragma unroll
    for (int xx = 0; xx < 4; ++xx)
#pragma unroll
      for (int y = 0; y < 4; ++y) {
        int col = s * 256 + n0 + wn * 64 + y * 16 + r;
#pragma unroll
        for (int g = 0; g < 4; ++g) {
          int cp = wm * 64 + xx * 16 + q * 4 + g;
          AVH[(size_t)(n * 128 + cp) * 512 + col] = f2bf(acc[xx][y][g]);
        }
      }
  }
}

// ---------------------------------------------------------------------------
// Fused layer-2 (R13): bandwidth shape, RACE-FREE loop. 128x128 tile,
// 256 thr, grid 2048, 32 KiB LDS. Main loop = proven gemm_bf16 structure:
// single-buffer pure global_load_lds staging (RH + u5b), __syncthreads
// discipline, NO manual waitcnt. Epilogue: R10's two-pass f32 LDS
// transpose (L[64][128], word-XOR swizzle) -> vectorized z/pv/out.
// ---------------------------------------------------------------------------
__global__ __launch_bounds__(256, 3) void gemm_l2(
    const unsigned short* __restrict__ PRE, const float* __restrict__ SG,
    const unsigned short* __restrict__ H1, const unsigned short* __restrict__ u5b,
    float* __restrict__ out)
{
  __shared__ __align__(16) unsigned short SM[16384];  // As|Bs (16 KB) ; L = f32[64][128] (32 KB)
  unsigned short* const As = SM;
  unsigned short* const Bs = SM + 4096;
  float* L = (float*)SM;

  const int t = threadIdx.x, bid = blockIdx.x;
  const int xcd = bid & 7, slot = bid >> 3;
  const int mt = xcd * 128 + (slot >> 1);
  const int nt = slot & 1;
  const int lane = t & 63, w = t >> 6, wm = w >> 1, wn = w & 1;
  const int r = lane & 15, q = lane >> 4;
  const int m0 = mt * 128, n0 = nt * 128;

  f32x4 acc[4][4] = {};

  for (int kb = 0; kb < 256; kb += 32) {
#pragma unroll
    for (int i = 0; i < 2; ++i) {
      int u  = i * 256 + t;
      int mi = u >> 2;
      int gc = (u & 3) ^ ((mi >> 1) & 3);
      __builtin_amdgcn_global_load_lds(GLOBAL_AS(PRE + (size_t)(m0 + mi) * 768 + 256 + kb + gc * 8),
                                       LDS_AS(&As[u * 8]), 16, 0, 0);
      __builtin_amdgcn_global_load_lds(GLOBAL_AS(u5b + (size_t)(n0 + mi) * 256 + kb + gc * 8),
                                       LDS_AS(&Bs[u * 8]), 16, 0, 0);
    }
    __syncthreads();

    frag af[4], bf_[4];
#pragma unroll
    for (int xx = 0; xx < 4; ++xx) {
      int ra = wm * 64 + xx * 16 + r;
      int rb = wn * 64 + xx * 16 + r;
      af[xx]  = *(const frag*)&As[ra * 32 + ((q ^ ((ra >> 1) & 3)) * 8)];
      bf_[xx] = *(const frag*)&Bs[rb * 32 + ((q ^ ((rb >> 1) & 3)) * 8)];
    }
#pragma unroll
    for (int xx = 0; xx < 4; ++xx)
#pragma unroll
      for (int y = 0; y < 4; ++y)
        acc[xx][y] = MFMA16(af[xx], bf_[y], acc[xx][y], 0, 0, 0);
    __syncthreads();
  }

  // ---- epilogue: two-pass f32 transpose through L[64][128] (swizzled) ----
  const int lr_r = t >> 2;     // read row 0..63
  const int cb   = t & 3;      // read col-block
#pragma unroll 1
  for (int p = 0; p < 2; ++p) {
    if (p) __syncthreads();                  // reads of pass 0 done before overwrite
    if (wm == p) {
#pragma unroll
      for (int xx = 0; xx < 4; ++xx)
#pragma unroll
        for (int y = 0; y < 4; ++y) {
          int j = wn * 64 + y * 16 + r;
#pragma unroll
          for (int g = 0; g < 4; ++g) {
            int lr = xx * 16 + q * 4 + g;
            L[lr * 128 + (j ^ ((lr & 7) << 2))] = acc[xx][y][g];
          }
        }
    }
    __syncthreads();
    long grow = m0 + p * 64 + lr_r;
    int cc = (int)(grow & 127);
    const unsigned short* prow = PRE + (size_t)grow * 768;
    const unsigned short* hrow = H1 + (size_t)grow * 256;
    const float* sgr = SG + (size_t)cc * 768;
    const int off = (lr_r & 7) << 2;
#pragma unroll
    for (int gi = 0; gi < 4; ++gi) {
      int j0 = cb * 8 + gi * 32;
      int i0 = n0 + j0;
      f32x4 a0 = *(const f32x4*)&L[lr_r * 128 + (j0 ^ off)];
      f32x4 a1 = *(const f32x4*)&L[lr_r * 128 + ((j0 + 4) ^ off)];
      frag pz = *(const frag*)(prow + i0);
      frag pp = *(const frag*)(prow + 512 + i0);
      frag hh = *(const frag*)(hrow + i0);
      f32x4 sz0 = *(const f32x4*)(sgr + i0);
      f32x4 sz1 = *(const f32x4*)(sgr + i0 + 4);
      f32x4 sp0 = *(const f32x4*)(sgr + 512 + i0);
      f32x4 sp1 = *(const f32x4*)(sgr + 512 + i0 + 4);
      f32x4 o0, o1;
#pragma unroll
      for (int e = 0; e < 8; ++e) {
        float sz = (e < 4) ? sz0[e] : sz1[e - 4];
        float sp = (e < 4) ? sp0[e] : sp1[e - 4];
        float av = (e < 4) ? a0[e] : a1[e - 4];
        float z  = sigm(sz + bf2f((unsigned short)pz[e]));
        float pv = sp + bf2f((unsigned short)pp[e]) + av;
        float h  = bf2f((unsigned short)hh[e]);
        float o  = (1.0f - z) * h + z * tanh_fast(pv);
        if (e < 4) o0[e] = o; else o1[e - 4] = o;
      }
      *(f32x4*)&out[(size_t)grow * 256 + i0] = o0;
      *(f32x4*)&out[(size_t)grow * 256 + i0 + 4] = o1;
    }
  }
}

// ---------------------------------------------------------------------------
// prep kernels
// ---------------------------------------------------------------------------
__global__ __launch_bounds__(256) void prep_cast(
    const float* __restrict__ x, const float* __restrict__ Kn,
    const float* __restrict__ w3, const float* __restrict__ u3,
    const float* __restrict__ w4, const float* __restrict__ w5,
    const float* __restrict__ u5,
    unsigned short* __restrict__ xb, unsigned short* __restrict__ WB,
    unsigned short* __restrict__ WB2, unsigned short* __restrict__ u5b,
    unsigned short* __restrict__ KbN, unsigned short* __restrict__ KTbN)
{
  int idx = blockIdx.x * 256 + threadIdx.x;
  if (idx < 262144) { xb[idx] = f2bf(x[idx]); return; }
  idx -= 262144;
  if (idx < 589824) {
    int col = idx / 768, j = idx % 768;
    int g = col >> 8, i = col & 255;
    float v;
    if (j < 512) { const float* wg = (g == 0) ? w3 : (g == 1) ? w4 : w5; v = wg[(size_t)i * 512 + j]; }
    else v = (g < 2) ? u3[(size_t)i * 256 + (j - 512)] : 0.0f;
    WB[(size_t)col * 768 + j] = f2bf(v);
    return;
  }
  idx -= 589824;
  if (idx < 458752) {
    int col = idx / 256, h = idx % 256;
    int b = col >> 8, i = col & 255;
    float v = (b < 6) ? ((b < 2 ? w3 : (b < 4 ? w4 : w5))[(size_t)i * 512 + (b & 1) * 256 + h])
                      : u3[(size_t)i * 256 + h];
    WB2[(size_t)col * 256 + h] = f2bf(v);
    return;
  }
  idx -= 458752;
  if (idx < 65536) { u5b[idx] = f2bf(u5[idx]); return; }
  idx -= 65536;
  if (idx < 16384) { int c = idx >> 7, k = idx & 127; KbN[idx]  = f2bf(-Kn[c * 128 + k]); return; }
  idx -= 16384;
  { int c = idx >> 7, k = idx & 127; KTbN[idx] = f2bf(-Kn[k * 128 + c]); }
}

__global__ __launch_bounds__(256) void prep_reduce(
    const float* __restrict__ x, const float* __restrict__ Kn,
    float* __restrict__ S, float* __restrict__ colsum, float* __restrict__ rowsum)
{
  int b = blockIdx.x, t = threadIdx.x;
  if (b < 8) {
    float s = 0.f;
    for (int n = 0; n < 128; ++n) s += x[(size_t)(b * 128 + n) * HID + t];
    atomicAdd(&S[t], s);
  } else if (b == 8) {
    if (t < NCLS) { float s = 0.f; for (int k = 0; k < NCLS; ++k) s += Kn[k * NCLS + t]; colsum[t] = s; }
  } else {
    if (t < NCLS) { float s = 0.f; for (int k = 0; k < NCLS; ++k) s += Kn[t * NCLS + k]; rowsum[t] = s; }
  }
}

__global__ __launch_bounds__(256) void prep_sw(
    const float* __restrict__ S, const float* __restrict__ w3,
    const float* __restrict__ w4, const float* __restrict__ w5, float* __restrict__ SW)
{
  int col = blockIdx.x * 256 + threadIdx.x;
  int b = col >> 8, i = col & 255;
  const float* w = (b < 2) ? w3 : (b < 4) ? w4 : w5;
  const float* row = w + (size_t)i * 512 + (b & 1) * 256;
  float s = 0.f;
  for (int h = 0; h < HID; ++h) s += S[h] * row[h];
  SW[col] = s;
}

__global__ __launch_bounds__(256) void reduce_hs(
    const unsigned short* __restrict__ H1, float* __restrict__ hs)
{
  int bid = blockIdx.x;
  int c = bid >> 5, nch = bid & 31;
  int i = threadIdx.x;
  const unsigned short* p = H1 + (size_t)nch * 32 * NCLS * HID + (size_t)c * HID + i;
  float s = 0.f;
  for (int n = 0; n < 32; ++n) s += bf2f(p[(size_t)n * NCLS * HID]);
  atomicAdd(&hs[c * HID + i], s);
}

__global__ __launch_bounds__(256) void p2a(
    const float* __restrict__ hs, const float* __restrict__ w3,
    const float* __restrict__ w4, const float* __restrict__ w5, float* __restrict__ hsW)
{
  __shared__ float hrow[HID];
  int k = blockIdx.x & 127, b = blockIdx.x >> 7;
  int t = threadIdx.x;
  hrow[t] = hs[k * HID + t];
  __syncthreads();
  const float* w = (b < 2) ? w3 : (b < 4) ? w4 : w5;
  const float* row = w + (size_t)t * 512 + (b & 1) * 256;
  float s = 0.f;
  for (int h = 0; h < HID; ++h) s += hrow[h] * row[h];
  hsW[(size_t)k * 1536 + b * 256 + t] = s;
}

__global__ __launch_bounds__(256) void p2b(
    const float* __restrict__ hsW, const float* __restrict__ Kn,
    const float* __restrict__ b3, const float* __restrict__ b4, const float* __restrict__ b5,
    const float* __restrict__ bu3, const float* __restrict__ bu5, float* __restrict__ SG)
{
  __shared__ float kc[NCLS], kr[NCLS];
  int c = blockIdx.x, t = threadIdx.x;
  if (t < NCLS) { kc[t] = Kn[t * NCLS + c]; kr[t] = Kn[c * NCLS + t]; }
  __syncthreads();
  for (int g = 0; g < 3; ++g) {
    int i = t;
    const float* L = hsW + (size_t)(2 * g) * 256 + i;
    const float* R = hsW + (size_t)(2 * g + 1) * 256 + i;
    float s = 0.f;
    for (int k = 0; k < NCLS; ++k) s += kc[k] * L[(size_t)k * 1536] + kr[k] * R[(size_t)k * 1536];
    const float* bg = (g == 0) ? b3 : (g == 1) ? b4 : b5;
    s += bg[i] + ((g < 2) ? bu3[i] : bu5[i]);
    SG[(size_t)c * 768 + g * 256 + i] = s;
  }
}

// ---------------------------------------------------------------------------
extern "C" void kernel_launch(void* const* d_in, const int* in_sizes, int n_in,
                              void* d_out, int out_size, void* d_ws, size_t ws_size,
                              hipStream_t stream) {
  (void)in_sizes; (void)n_in; (void)out_size; (void)ws_size;
  const float* x   = (const float*)d_in[0];
  const float* Kn  = (const float*)d_in[1];
  const float* w3  = (const float*)d_in[2];
  const float* b3  = (const float*)d_in[3];
  const float* u3  = (const float*)d_in[4];
  const float* bu3 = (const float*)d_in[5];
  const float* w4  = (const float*)d_in[6];
  const float* b4  = (const float*)d_in[7];
  const float* w5  = (const float*)d_in[8];
  const float* b5  = (const float*)d_in[9];
  const float* u5  = (const float*)d_in[10];
  const float* bu5 = (const float*)d_in[11];
  float* out = (float*)d_out;

  char* w = (char*)d_ws;
  unsigned short* AVH = (unsigned short*)(w);                 // 131072x512 bf16 (128 MiB)
  unsigned short* PRE = (unsigned short*)(w + 134217728);     // 131072x768 bf16 (192 MiB)
  unsigned short* H1  = (unsigned short*)(w + 335544320);     // 64 MiB
  float*          XW  = (float*)(w + 402653184);              // 1024x1792 fp32
  char* misc = w + 409993216;
  float* S      = (float*)(misc);
  float* hs     = (float*)(misc + 1024);
  float* SW     = (float*)(misc + 132096);
  float* colsum = (float*)(misc + 138240);
  float* rowsum = (float*)(misc + 138752);
  float* hsW    = (float*)(misc + 139264);
  float* SG     = (float*)(misc + 925696);
  unsigned short* WB   = (unsigned short*)(misc + 1318912);
  unsigned short* WB2  = (unsigned short*)(misc + 2498560);
  unsigned short* u5b  = (unsigned short*)(misc + 3416064);
  unsigned short* KbN  = (unsigned short*)(misc + 3547136);
  unsigned short* KTbN = (unsigned short*)(misc + 3579904);
  unsigned short* xb   = (unsigned short*)(misc + 3612672);

  hipMemsetAsync(misc, 0, 132096, stream);  // S + hs

  prep_cast<<<5504, 256, 0, stream>>>(x, Kn, w3, u3, w4, w5, u5, xb, WB, WB2, u5b, KbN, KTbN);
  prep_reduce<<<10, 256, 0, stream>>>(x, Kn, S, colsum, rowsum);
  prep_sw<<<6, 256, 0, stream>>>(S, w3, w4, w5, SW);

  // XW = x @ Wcat^T  [1024,256]x[256,1792] -> fp32
  gemm_bf16<0><<<8 * 14, 256, 0, stream>>>(xb, 256, 256, xb, 256, WB2, 256, 0L,
                                           (void*)XW, 1792, 14, 256, 0xFFFFFFFFu, 8);
  // fused layer 1 -> H1 and AVH (mini-GEMMs in epilogue)
  gemm_l1<<<2048, 256, 0, stream>>>(XW, SW, x, b3, b4, b5, bu3, bu5,
                                    colsum, rowsum, u5b, KTbN, KbN, H1, AVH);

  reduce_hs<<<4096, 256, 0, stream>>>(H1, hs);
  p2a<<<768, 256, 0, stream>>>(hs, w3, w4, w5, hsW);
  p2b<<<128, 256, 0, stream>>>(hsW, Kn, b3, b4, b5, bu3, bu5, SG);

  // PRE: 256x256-tile 4-phase pipelined kernel; ct==1 writes RH (fused l2 prep)
  gemm_pre<<<1536, 512, 0, stream>>>(AVH, H1, WB, SG, PRE);

  // fused layer 2 -> out (streaming GEMM on RH + vectorized epilogue)
  gemm_l2<<<2048, 256, 0, stream>>>(PRE, SG, H1, u5b, out);
}

// Round 9
// 677.301 us; speedup vs baseline: 1.2442x; 1.0132x over previous
//
#include <hip/hip_runtime.h>
#include <cstdint>
#include <cstddef>

// ---------------------------------------------------------------------------
// Graph_8564164788735: 2-layer class-conditioned GRU-ish propagation.
// N=1024 nodes, C=128 classes, H=256. Output fp32 [N,C,H].
//
// R14: gemm_l1 As/Bs double-buffered — the sigm-heavy As-prep (160 VALU
// ops/thread/K-step) was serialized between barriers against 16 MFMAs
// (R7 counters: VALU 47.7%, Mfma 6.6% = summed, not maxed). Now per iter:
// read frags(kb) -> issue Bs-stage(kb+32) + prep As(kb+32) into cur^1
// (independent of MFMA; compiler interleaves VALU with MFMA) -> MFMA(kb)
// -> ONE __syncthreads() (full drain; race-free, no manual waitcnt).
// Numerics bit-identical. gemm_pre (R11 RH fusion) and gemm_l2 (R13
// race-free bandwidth shape) unchanged.
// ---------------------------------------------------------------------------

#define NODES 1024
#define NCLS  128
#define HID   256

using frag  = __attribute__((ext_vector_type(8))) short;
using frag4 = __attribute__((ext_vector_type(4))) short;
using f32x4 = __attribute__((ext_vector_type(4))) float;

__device__ __forceinline__ float bf2f(unsigned short h){
  unsigned int u = ((unsigned int)h) << 16;
  float f; __builtin_memcpy(&f, &u, 4); return f;
}
__device__ __forceinline__ unsigned short f2bf(float f){
  unsigned int u; __builtin_memcpy(&u, &f, 4);
  u = (u + 0x7fffu + ((u >> 16) & 1u)) >> 16;   // RNE
  return (unsigned short)u;
}
__device__ __forceinline__ float sigm(float x){ return 1.0f/(1.0f + __expf(-x)); }
__device__ __forceinline__ float tanh_fast(float x){ return 1.0f - 2.0f/(__expf(2.0f*x) + 1.0f); }

#define GLOBAL_AS(p) ((const __attribute__((address_space(1))) void*)(p))
#define LDS_AS(p)    ((__attribute__((address_space(3))) void*)(p))
#define MFMA16 __builtin_amdgcn_mfma_f32_16x16x32_bf16

// ---------------------------------------------------------------------------
// Generic bf16 MFMA GEMM (only used for XW). 128x128 tile, BK=32.
// ---------------------------------------------------------------------------
template<int OUT_BF16>
__global__ __launch_bounds__(256) void gemm_bf16(
    const unsigned short* __restrict__ A0, int ldA0, int K0,
    const unsigned short* __restrict__ A1, int ldA1,
    const unsigned short* __restrict__ BT, int ldB, long bStride,
    void* __restrict__ Cptr, int ldC,
    int Ntiles, int Ktot, unsigned int aMask, int Mtiles)
{
  __shared__ unsigned short As[4096];
  __shared__ unsigned short Bs[4096];
  const int t   = threadIdx.x;
  const int bid = blockIdx.x;
  const int xcd = bid & 7, slot = bid >> 3;
  const int mtPerX = (Mtiles >= 8) ? (Mtiles >> 3) : 1;
  const int mt = xcd * mtPerX + slot / Ntiles;
  const int nt = slot % Ntiles;
  const int lane = t & 63, w = t >> 6;
  const int wm = w >> 1, wn = w & 1;
  const int r = lane & 15, q = lane >> 4;
  const int m0 = mt * 128, n0 = nt * 128;
  const unsigned short* Bbase = BT + (size_t)mt * (size_t)bStride;

  f32x4 acc[4][4] = {};

  for (int kb = 0; kb < Ktot; kb += 32) {
#pragma unroll
    for (int i = 0; i < 2; ++i) {
      int u  = i * 256 + t;
      int mi = u >> 2;
      int kc = (u & 3) * 8;
      int k  = kb + kc;
      const unsigned short* ga;
      if (k < K0) ga = A0 + (size_t)((unsigned int)(m0 + mi) & aMask) * (size_t)ldA0 + k;
      else        ga = A1 + (size_t)(m0 + mi) * (size_t)ldA1 + (k - K0);
      __builtin_amdgcn_global_load_lds(GLOBAL_AS(ga), LDS_AS(&As[u * 8]), 16, 0, 0);
      const unsigned short* gb = Bbase + (size_t)(n0 + mi) * (size_t)ldB + k;
      __builtin_amdgcn_global_load_lds(GLOBAL_AS(gb), LDS_AS(&Bs[u * 8]), 16, 0, 0);
    }
    __syncthreads();

    frag af[4], bf_[4];
#pragma unroll
    for (int x = 0; x < 4; ++x) {
      af[x]  = *(const frag*)&As[(wm * 64 + x * 16 + r) * 32 + q * 8];
      bf_[x] = *(const frag*)&Bs[(wn * 64 + x * 16 + r) * 32 + q * 8];
    }
#pragma unroll
    for (int x = 0; x < 4; ++x)
#pragma unroll
      for (int y = 0; y < 4; ++y)
        acc[x][y] = MFMA16(af[x], bf_[y], acc[x][y], 0, 0, 0);
    __syncthreads();
  }

#pragma unroll
  for (int x = 0; x < 4; ++x) {
#pragma unroll
    for (int y = 0; y < 4; ++y) {
      int col = n0 + wn * 64 + y * 16 + r;
#pragma unroll
      for (int g = 0; g < 4; ++g) {
        long row = m0 + wm * 64 + x * 16 + q * 4 + g;
        if (OUT_BF16) ((unsigned short*)Cptr)[row * (long)ldC + col] = f2bf(acc[x][y][g]);
        else          ((float*)Cptr)[row * (long)ldC + col] = acc[x][y][g];
      }
    }
  }
}

// ---------------------------------------------------------------------------
// gemm_pre (R11): R9 4-phase pipeline; ct==1 epilogue fuses l2's As-prep:
// RH = sigm(SG4 + pre4) * H1, written into PRE's gate-4 slot.
// ---------------------------------------------------------------------------
__global__ __launch_bounds__(512, 2) void gemm_pre(
    const unsigned short* __restrict__ AVH, const unsigned short* __restrict__ H1,
    const unsigned short* __restrict__ WB, const float* __restrict__ SG,
    unsigned short* __restrict__ PRE)
{
  __shared__ __align__(16) unsigned short SM[65536];   // 128 KiB
  const int t   = threadIdx.x;
  const int bid = blockIdx.x;
  const int xcd = bid & 7, slot = bid >> 3;
  const int mt = xcd * 64 + slot / 3;
  const int ct = slot % 3;
  const int lane = t & 63, w = t >> 6;
  const int wm = w >> 2, wn = w & 3;          // 2M x 4N waves
  const int r = lane & 15, q = lane >> 4;
  const int m0 = mt * 256;
  const unsigned short* Wrow = WB + (size_t)(ct * 256) * 768;
  const int nkt = (ct < 2) ? 12 : 8;          // K-tiles of 64

  unsigned short* const Ab0 = SM;
  unsigned short* const Ab1 = SM + 16384;
  unsigned short* const Bb0 = SM + 32768;
  unsigned short* const Bb1 = SM + 49152;

  f32x4 acc[8][4] = {};

  const int smi = t >> 3, sc = t & 7;         // staging: row-in-round, chunk

  auto ISSUE_A = [&](unsigned short* dst, int kt, int rbase) {
    int row = rbase + smi;
    int gc = sc ^ (row & 7);
    const unsigned short* ga;
    if (kt < 8) ga = AVH + (size_t)(m0 + row) * 512 + kt * 64 + gc * 8;
    else        ga = H1  + (size_t)(m0 + row) * 256 + (kt - 8) * 64 + gc * 8;
    __builtin_amdgcn_global_load_lds(GLOBAL_AS(ga), LDS_AS(&dst[row * 64 + sc * 8]), 16, 0, 0);
  };
  auto ISSUE_B = [&](unsigned short* dst, int kt, int rbase) {
    int row = rbase + smi;
    int gc = sc ^ (row & 7);
    __builtin_amdgcn_global_load_lds(GLOBAL_AS(Wrow + (size_t)row * 768 + kt * 64 + gc * 8),
                                     LDS_AS(&dst[row * 64 + sc * 8]), 16, 0, 0);
  };

  // prologue: stage tile 0 in the canonical order
  ISSUE_B(Bb0, 0, 0); ISSUE_B(Bb0, 0, 64); ISSUE_B(Bb0, 0, 128); ISSUE_B(Bb0, 0, 192);
  ISSUE_A(Ab0, 0, 0); ISSUE_A(Ab0, 0, 128); ISSUE_A(Ab0, 0, 64); ISSUE_A(Ab0, 0, 192);
  asm volatile("s_waitcnt vmcnt(2)" ::: "memory");
  __builtin_amdgcn_s_barrier();

#define PRE_PHASE(XG0, ISSUES, TAIL)                                         \
    {                                                                        \
      int ra0 = wm * 128 + (XG0) * 16 + r, ra1 = ra0 + 16;                   \
      frag a00 = *(const frag*)&A[ra0 * 64 + ((q ^ (ra0 & 7)) * 8)];         \
      frag a01 = *(const frag*)&A[ra0 * 64 + (((4 + q) ^ (ra0 & 7)) * 8)];   \
      frag a10 = *(const frag*)&A[ra1 * 64 + ((q ^ (ra1 & 7)) * 8)];         \
      frag a11 = *(const frag*)&A[ra1 * 64 + (((4 + q) ^ (ra1 & 7)) * 8)];   \
      ISSUES;                                                                \
      __builtin_amdgcn_s_setprio(1);                                         \
      _Pragma("unroll")                                                      \
      for (int y = 0; y < 4; ++y) {                                          \
        acc[(XG0)][y]     = MFMA16(a00, bf[y][0], acc[(XG0)][y], 0, 0, 0);   \
        acc[(XG0)][y]     = MFMA16(a01, bf[y][1], acc[(XG0)][y], 0, 0, 0);   \
        acc[(XG0)+1][y]   = MFMA16(a10, bf[y][0], acc[(XG0)+1][y], 0, 0, 0); \
        acc[(XG0)+1][y]   = MFMA16(a11, bf[y][1], acc[(XG0)+1][y], 0, 0, 0); \
      }                                                                      \
      __builtin_amdgcn_s_setprio(0);                                         \
      TAIL;                                                                  \
      asm volatile("" ::: "memory");                                         \
      __builtin_amdgcn_s_barrier();                                          \
    }

  for (int kt = 0; kt < nkt; ++kt) {
    unsigned short* A  = (kt & 1) ? Ab1 : Ab0;
    unsigned short* B  = (kt & 1) ? Bb1 : Bb0;
    unsigned short* An = (kt & 1) ? Ab0 : Ab1;
    unsigned short* Bn = (kt & 1) ? Bb0 : Bb1;
    const bool more = (kt + 1 < nkt);

    frag bf[4][2];
#pragma unroll
    for (int y = 0; y < 4; ++y) {
      int rb = wn * 64 + y * 16 + r;
      bf[y][0] = *(const frag*)&B[rb * 64 + ((q ^ (rb & 7)) * 8)];
      bf[y][1] = *(const frag*)&B[rb * 64 + (((4 + q) ^ (rb & 7)) * 8)];
    }

    PRE_PHASE(0,
      { if (more) { ISSUE_B(Bn, kt + 1, 0); ISSUE_B(Bn, kt + 1, 64); } },
      { })
    PRE_PHASE(2,
      { if (more) { ISSUE_B(Bn, kt + 1, 128); ISSUE_B(Bn, kt + 1, 192); } },
      { if (more) asm volatile("s_waitcnt vmcnt(4)" ::: "memory");
        else      asm volatile("s_waitcnt vmcnt(0)" ::: "memory"); })
    PRE_PHASE(4,
      { if (more) { ISSUE_A(An, kt + 1, 0); ISSUE_A(An, kt + 1, 128); } },
      { })
    PRE_PHASE(6,
      { if (more) { ISSUE_A(An, kt + 1, 64); ISSUE_A(An, kt + 1, 192); } },
      { if (more) asm volatile("s_waitcnt vmcnt(2)" ::: "memory"); })
  }
#undef PRE_PHASE

  // epilogue: acc -> L[256][256] (chunk swizzle jc^(c&31)) -> full lines
  unsigned short* L = SM;
#pragma unroll
  for (int xg = 0; xg < 8; ++xg) {
#pragma unroll
    for (int y = 0; y < 4; ++y) {
      int j = wn * 64 + y * 16 + r;
      int jc = j >> 3, jl = j & 7;
#pragma unroll
      for (int g = 0; g < 4; ++g) {
        int c = wm * 128 + xg * 16 + q * 4 + g;
        L[c * 256 + ((jc ^ (c & 31)) * 8) + jl] = f2bf(acc[xg][y][g]);
      }
    }
  }
  __syncthreads();
  if (ct == 1) {
    // fused l2 As-prep: RH = sigm(SG4 + pre4) * H1 -> PRE gate-4 slot
#pragma unroll
    for (int rr = 0; rr < 16; ++rr) {
      int unit = rr * 512 + t;
      int row = unit >> 5, ch = unit & 31;
      size_t grow = (size_t)(m0 + row);
      frag v  = *(const frag*)&L[row * 256 + ((ch ^ (row & 31)) * 8)];
      frag hh = *(const frag*)(H1 + grow * 256 + ch * 8);
      const float* sgr = SG + (size_t)(row & 127) * 768 + 256 + ch * 8;
      f32x4 s0 = *(const f32x4*)(sgr);
      f32x4 s1 = *(const f32x4*)(sgr + 4);
      frag o;
#pragma unroll
      for (int e = 0; e < 8; ++e) {
        float sv = (e < 4) ? s0[e] : s1[e - 4];
        float rv = sigm(sv + bf2f((unsigned short)v[e]));
        o[e] = (short)f2bf(rv * bf2f((unsigned short)hh[e]));
      }
      *(frag*)&PRE[grow * 768 + 256 + ch * 8] = o;
    }
  } else {
#pragma unroll
    for (int rr = 0; rr < 16; ++rr) {
      int unit = rr * 512 + t;
      int row = unit >> 5, ch = unit & 31;
      frag v = *(const frag*)&L[row * 256 + ((ch ^ (row & 31)) * 8)];
      *(frag*)&PRE[(size_t)(m0 + row) * 768 + ct * 256 + ch * 8] = v;
    }
  }
}

// ---------------------------------------------------------------------------
// Fused layer-1 (R14): As/Bs double-buffered. Per iter: read frags(kb) ->
// issue Bs-stage(kb+32) + VALU As-prep(kb+32) into cur^1 (overlaps MFMA) ->
// MFMA(kb) -> ONE __syncthreads (full drain; race-free). Epilogues as R8.
// LDS: As dbuf [0:8192] | Bs dbuf [8192:16384]; L=SM (epi, 17408 shorts).
// ---------------------------------------------------------------------------
__global__ __launch_bounds__(256, 2) void gemm_l1(
    const float* __restrict__ XW, const float* __restrict__ SW,
    const float* __restrict__ x,
    const float* __restrict__ b3, const float* __restrict__ b4,
    const float* __restrict__ b5, const float* __restrict__ bu3,
    const float* __restrict__ bu5,
    const float* __restrict__ colsum, const float* __restrict__ rowsum,
    const unsigned short* __restrict__ u5b,
    const unsigned short* __restrict__ KTbN, const unsigned short* __restrict__ KbN,
    unsigned short* __restrict__ H1, unsigned short* __restrict__ AVH)
{
  __shared__ unsigned short SM[17408];   // As dbuf | Bs dbuf ; L = SM (epi)
  unsigned short* L  = SM;               // [128 j][136] : L[j][c] = h1[c][j]
  __shared__ float tP1[256], tP2[256], tP3[256], tX[256];
  __shared__ float tZ1[256], tZ2[256], tZ3[256];
  __shared__ float tV1[256], tV2[256], tV3[256];
  __shared__ float tCS[128], tRS[128];

  const int t = threadIdx.x, bid = blockIdx.x;
  const int xcd = bid & 7, slot = bid >> 3;
  const int n  = xcd * 128 + (slot >> 1);
  const int nt = slot & 1;
  const int lane = t & 63, w = t >> 6, wm = w >> 1, wn = w & 1;
  const int r = lane & 15, q = lane >> 4;
  const int n0 = nt * 128;
  const float* xw = XW + (size_t)n * 1792;

  {
    int i = t;
    float xwi0 = xw[i], xwi1 = xw[256 + i], xwi2 = xw[512 + i], xwi3 = xw[768 + i];
    float xwi4 = xw[1024 + i], xwi5 = xw[1280 + i], xwu = xw[1536 + i];
    tP1[i] = SW[512 + i] - xwi2;
    tP2[i] = SW[768 + i] - xwi3;
    tP3[i] = xwu + b4[i] + bu3[i];
    tX[i]  = x[(size_t)n * HID + i];
    tZ1[i] = SW[i] - xwi0;
    tZ2[i] = SW[256 + i] - xwi1;
    tZ3[i] = xwu + b3[i] + bu3[i];
    tV1[i] = SW[1024 + i] - xwi4;
    tV2[i] = SW[1280 + i] - xwi5;
    tV3[i] = b5[i] + bu5[i];
    if (t < 128) { tCS[t] = colsum[t]; tRS[t] = rowsum[t]; }
  }
  __syncthreads();

  auto PREP_A = [&](unsigned short* Asb, int kb) {
#pragma unroll
    for (int i = 0; i < 2; ++i) {
      int u  = i * 256 + t;
      int mi = u >> 2;
      int c  = u & 3;
      int k  = kb + c * 8;
      int gc = c ^ ((mi >> 1) & 3);
      float cs = tCS[mi], rs = tRS[mi];
      frag a;
#pragma unroll
      for (int e = 0; e < 8; ++e) {
        int i2 = k + e;
        float pre = cs * tP1[i2] + rs * tP2[i2] + tP3[i2];
        a[e] = (short)f2bf(sigm(pre) * tX[i2]);
      }
      *(frag*)&Asb[mi * 32 + (gc * 8)] = a;
    }
  };
  auto STAGE_B = [&](unsigned short* Bsb, int kb) {
#pragma unroll
    for (int i = 0; i < 2; ++i) {
      int u  = i * 256 + t;
      int mi = u >> 2;
      int c  = u & 3;
      int gc = c ^ ((mi >> 1) & 3);
      __builtin_amdgcn_global_load_lds(GLOBAL_AS(u5b + (size_t)(n0 + mi) * 256 + kb + gc * 8),
                                       LDS_AS(&Bsb[u * 8]), 16, 0, 0);
    }
  };

  PREP_A(SM, 0);
  STAGE_B(SM + 8192, 0);
  __syncthreads();

  f32x4 acc[4][4] = {};

  for (int kb = 0; kb < 256; kb += 32) {
    const int cur = (kb >> 5) & 1;
    const unsigned short* Asb = SM + cur * 4096;
    const unsigned short* Bsb = SM + 8192 + cur * 4096;

    frag af[4], bf_[4];
#pragma unroll
    for (int xx = 0; xx < 4; ++xx) {
      int ra = wm * 64 + xx * 16 + r;
      int rb = wn * 64 + xx * 16 + r;
      af[xx]  = *(const frag*)&Asb[ra * 32 + ((q ^ ((ra >> 1) & 3)) * 8)];
      bf_[xx] = *(const frag*)&Bsb[rb * 32 + ((q ^ ((rb >> 1) & 3)) * 8)];
    }

    if (kb < 224) {
      STAGE_B(SM + 8192 + (cur ^ 1) * 4096, kb + 32);
      PREP_A(SM + (cur ^ 1) * 4096, kb + 32);   // VALU overlaps MFMA below
    }

#pragma unroll
    for (int xx = 0; xx < 4; ++xx)
#pragma unroll
      for (int y = 0; y < 4; ++y)
        acc[xx][y] = MFMA16(af[xx], bf_[y], acc[xx][y], 0, 0, 0);
    __syncthreads();
  }

  // epilogue 1: GRU update -> H1 (global) and L[j][c]=h1[c][j] (LDS)
#pragma unroll
  for (int xx = 0; xx < 4; ++xx) {
#pragma unroll
    for (int y = 0; y < 4; ++y) {
      int j = wn * 64 + y * 16 + r;        // local hidden col
      int i = n0 + j;                      // global hidden col
      frag4 pack;
#pragma unroll
      for (int g = 0; g < 4; ++g) {
        int c = wm * 64 + xx * 16 + q * 4 + g;
        float cs = tCS[c], rs = tRS[c];
        float z  = sigm(cs * tZ1[i] + rs * tZ2[i] + tZ3[i]);
        float p5 = cs * tV1[i] + rs * tV2[i] + tV3[i] + acc[xx][y][g];
        float h1 = (1.0f - z) * tX[i] + z * tanh_fast(p5);
        unsigned short hb = f2bf(h1);
        pack[g] = (short)hb;
        H1[(size_t)(n * 128 + c) * HID + i] = hb;
      }
      *(frag4*)&L[j * 136 + (wm * 64 + xx * 16 + q * 4)] = pack;
    }
  }
  __syncthreads();

  // epilogue 2: AVH_n[:, s*256 + n0 + j] = sum_c Ksrc[c',c] * h1[c][j]
  // REUSES acc (re-zeroed) so AGPR peak stays at 64.
#pragma unroll 1
  for (int s = 0; s < 2; ++s) {
    const unsigned short* Ks = s ? KbN : KTbN;
#pragma unroll
    for (int xx = 0; xx < 4; ++xx)
#pragma unroll
      for (int y = 0; y < 4; ++y)
        acc[xx][y] = (f32x4){0.0f, 0.0f, 0.0f, 0.0f};
#pragma unroll
    for (int kb = 0; kb < 4; ++kb) {
      frag af[4], bf_[4];
#pragma unroll
      for (int xx = 0; xx < 4; ++xx) {
        int cp = wm * 64 + xx * 16 + r;
        af[xx] = *(const frag*)(Ks + (size_t)cp * 128 + kb * 32 + q * 8);
        int j = wn * 64 + xx * 16 + r;
        bf_[xx] = *(const frag*)&L[j * 136 + kb * 32 + q * 8];
      }
#pragma unroll
      for (int xx = 0; xx < 4; ++xx)
#pragma unroll
        for (int y = 0; y < 4; ++y)
          acc[xx][y] = MFMA16(af[xx], bf_[y], acc[xx][y], 0, 0, 0);
    }
#pragma unroll
    for (int xx = 0; xx < 4; ++xx)
#pragma unroll
      for (int y = 0; y < 4; ++y) {
        int col = s * 256 + n0 + wn * 64 + y * 16 + r;
#pragma unroll
        for (int g = 0; g < 4; ++g) {
          int cp = wm * 64 + xx * 16 + q * 4 + g;
          AVH[(size_t)(n * 128 + cp) * 512 + col] = f2bf(acc[xx][y][g]);
        }
      }
  }
}

// ---------------------------------------------------------------------------
// Fused layer-2 (R13): bandwidth shape, RACE-FREE loop. 128x128 tile,
// 256 thr, grid 2048, 32 KiB LDS. Main loop = proven gemm_bf16 structure:
// single-buffer pure global_load_lds staging (RH + u5b), __syncthreads
// discipline, NO manual waitcnt. Epilogue: R10's two-pass f32 LDS
// transpose (L[64][128], word-XOR swizzle) -> vectorized z/pv/out.
// ---------------------------------------------------------------------------
__global__ __launch_bounds__(256, 3) void gemm_l2(
    const unsigned short* __restrict__ PRE, const float* __restrict__ SG,
    const unsigned short* __restrict__ H1, const unsigned short* __restrict__ u5b,
    float* __restrict__ out)
{
  __shared__ __align__(16) unsigned short SM[16384];  // As|Bs (16 KB) ; L = f32[64][128] (32 KB)
  unsigned short* const As = SM;
  unsigned short* const Bs = SM + 4096;
  float* L = (float*)SM;

  const int t = threadIdx.x, bid = blockIdx.x;
  const int xcd = bid & 7, slot = bid >> 3;
  const int mt = xcd * 128 + (slot >> 1);
  const int nt = slot & 1;
  const int lane = t & 63, w = t >> 6, wm = w >> 1, wn = w & 1;
  const int r = lane & 15, q = lane >> 4;
  const int m0 = mt * 128, n0 = nt * 128;

  f32x4 acc[4][4] = {};

  for (int kb = 0; kb < 256; kb += 32) {
#pragma unroll
    for (int i = 0; i < 2; ++i) {
      int u  = i * 256 + t;
      int mi = u >> 2;
      int gc = (u & 3) ^ ((mi >> 1) & 3);
      __builtin_amdgcn_global_load_lds(GLOBAL_AS(PRE + (size_t)(m0 + mi) * 768 + 256 + kb + gc * 8),
                                       LDS_AS(&As[u * 8]), 16, 0, 0);
      __builtin_amdgcn_global_load_lds(GLOBAL_AS(u5b + (size_t)(n0 + mi) * 256 + kb + gc * 8),
                                       LDS_AS(&Bs[u * 8]), 16, 0, 0);
    }
    __syncthreads();

    frag af[4], bf_[4];
#pragma unroll
    for (int xx = 0; xx < 4; ++xx) {
      int ra = wm * 64 + xx * 16 + r;
      int rb = wn * 64 + xx * 16 + r;
      af[xx]  = *(const frag*)&As[ra * 32 + ((q ^ ((ra >> 1) & 3)) * 8)];
      bf_[xx] = *(const frag*)&Bs[rb * 32 + ((q ^ ((rb >> 1) & 3)) * 8)];
    }
#pragma unroll
    for (int xx = 0; xx < 4; ++xx)
#pragma unroll
      for (int y = 0; y < 4; ++y)
        acc[xx][y] = MFMA16(af[xx], bf_[y], acc[xx][y], 0, 0, 0);
    __syncthreads();
  }

  // ---- epilogue: two-pass f32 transpose through L[64][128] (swizzled) ----
  const int lr_r = t >> 2;     // read row 0..63
  const int cb   = t & 3;      // read col-block
#pragma unroll 1
  for (int p = 0; p < 2; ++p) {
    if (p) __syncthreads();                  // reads of pass 0 done before overwrite
    if (wm == p) {
#pragma unroll
      for (int xx = 0; xx < 4; ++xx)
#pragma unroll
        for (int y = 0; y < 4; ++y) {
          int j = wn * 64 + y * 16 + r;
#pragma unroll
          for (int g = 0; g < 4; ++g) {
            int lr = xx * 16 + q * 4 + g;
            L[lr * 128 + (j ^ ((lr & 7) << 2))] = acc[xx][y][g];
          }
        }
    }
    __syncthreads();
    long grow = m0 + p * 64 + lr_r;
    int cc = (int)(grow & 127);
    const unsigned short* prow = PRE + (size_t)grow * 768;
    const unsigned short* hrow = H1 + (size_t)grow * 256;
    const float* sgr = SG + (size_t)cc * 768;
    const int off = (lr_r & 7) << 2;
#pragma unroll
    for (int gi = 0; gi < 4; ++gi) {
      int j0 = cb * 8 + gi * 32;
      int i0 = n0 + j0;
      f32x4 a0 = *(const f32x4*)&L[lr_r * 128 + (j0 ^ off)];
      f32x4 a1 = *(const f32x4*)&L[lr_r * 128 + ((j0 + 4) ^ off)];
      frag pz = *(const frag*)(prow + i0);
      frag pp = *(const frag*)(prow + 512 + i0);
      frag hh = *(const frag*)(hrow + i0);
      f32x4 sz0 = *(const f32x4*)(sgr + i0);
      f32x4 sz1 = *(const f32x4*)(sgr + i0 + 4);
      f32x4 sp0 = *(const f32x4*)(sgr + 512 + i0);
      f32x4 sp1 = *(const f32x4*)(sgr + 512 + i0 + 4);
      f32x4 o0, o1;
#pragma unroll
      for (int e = 0; e < 8; ++e) {
        float sz = (e < 4) ? sz0[e] : sz1[e - 4];
        float sp = (e < 4) ? sp0[e] : sp1[e - 4];
        float av = (e < 4) ? a0[e] : a1[e - 4];
        float z  = sigm(sz + bf2f((unsigned short)pz[e]));
        float pv = sp + bf2f((unsigned short)pp[e]) + av;
        float h  = bf2f((unsigned short)hh[e]);
        float o  = (1.0f - z) * h + z * tanh_fast(pv);
        if (e < 4) o0[e] = o; else o1[e - 4] = o;
      }
      *(f32x4*)&out[(size_t)grow * 256 + i0] = o0;
      *(f32x4*)&out[(size_t)grow * 256 + i0 + 4] = o1;
    }
  }
}

// ---------------------------------------------------------------------------
// prep kernels
// ---------------------------------------------------------------------------
__global__ __launch_bounds__(256) void prep_cast(
    const float* __restrict__ x, const float* __restrict__ Kn,
    const float* __restrict__ w3, const float* __restrict__ u3,
    const float* __restrict__ w4, const float* __restrict__ w5,
    const float* __restrict__ u5,
    unsigned short* __restrict__ xb, unsigned short* __restrict__ WB,
    unsigned short* __restrict__ WB2, unsigned short* __restrict__ u5b,
    unsigned short* __restrict__ KbN, unsigned short* __restrict__ KTbN)
{
  int idx = blockIdx.x * 256 + threadIdx.x;
  if (idx < 262144) { xb[idx] = f2bf(x[idx]); return; }
  idx -= 262144;
  if (idx < 589824) {
    int col = idx / 768, j = idx % 768;
    int g = col >> 8, i = col & 255;
    float v;
    if (j < 512) { const float* wg = (g == 0) ? w3 : (g == 1) ? w4 : w5; v = wg[(size_t)i * 512 + j]; }
    else v = (g < 2) ? u3[(size_t)i * 256 + (j - 512)] : 0.0f;
    WB[(size_t)col * 768 + j] = f2bf(v);
    return;
  }
  idx -= 589824;
  if (idx < 458752) {
    int col = idx / 256, h = idx % 256;
    int b = col >> 8, i = col & 255;
    float v = (b < 6) ? ((b < 2 ? w3 : (b < 4 ? w4 : w5))[(size_t)i * 512 + (b & 1) * 256 + h])
                      : u3[(size_t)i * 256 + h];
    WB2[(size_t)col * 256 + h] = f2bf(v);
    return;
  }
  idx -= 458752;
  if (idx < 65536) { u5b[idx] = f2bf(u5[idx]); return; }
  idx -= 65536;
  if (idx < 16384) { int c = idx >> 7, k = idx & 127; KbN[idx]  = f2bf(-Kn[c * 128 + k]); return; }
  idx -= 16384;
  { int c = idx >> 7, k = idx & 127; KTbN[idx] = f2bf(-Kn[k * 128 + c]); }
}

__global__ __launch_bounds__(256) void prep_reduce(
    const float* __restrict__ x, const float* __restrict__ Kn,
    float* __restrict__ S, float* __restrict__ colsum, float* __restrict__ rowsum)
{
  int b = blockIdx.x, t = threadIdx.x;
  if (b < 8) {
    float s = 0.f;
    for (int n = 0; n < 128; ++n) s += x[(size_t)(b * 128 + n) * HID + t];
    atomicAdd(&S[t], s);
  } else if (b == 8) {
    if (t < NCLS) { float s = 0.f; for (int k = 0; k < NCLS; ++k) s += Kn[k * NCLS + t]; colsum[t] = s; }
  } else {
    if (t < NCLS) { float s = 0.f; for (int k = 0; k < NCLS; ++k) s += Kn[t * NCLS + k]; rowsum[t] = s; }
  }
}

__global__ __launch_bounds__(256) void prep_sw(
    const float* __restrict__ S, const float* __restrict__ w3,
    const float* __restrict__ w4, const float* __restrict__ w5, float* __restrict__ SW)
{
  int col = blockIdx.x * 256 + threadIdx.x;
  int b = col >> 8, i = col & 255;
  const float* w = (b < 2) ? w3 : (b < 4) ? w4 : w5;
  const float* row = w + (size_t)i * 512 + (b & 1) * 256;
  float s = 0.f;
  for (int h = 0; h < HID; ++h) s += S[h] * row[h];
  SW[col] = s;
}

__global__ __launch_bounds__(256) void reduce_hs(
    const unsigned short* __restrict__ H1, float* __restrict__ hs)
{
  int bid = blockIdx.x;
  int c = bid >> 5, nch = bid & 31;
  int i = threadIdx.x;
  const unsigned short* p = H1 + (size_t)nch * 32 * NCLS * HID + (size_t)c * HID + i;
  float s = 0.f;
  for (int n = 0; n < 32; ++n) s += bf2f(p[(size_t)n * NCLS * HID]);
  atomicAdd(&hs[c * HID + i], s);
}

__global__ __launch_bounds__(256) void p2a(
    const float* __restrict__ hs, const float* __restrict__ w3,
    const float* __restrict__ w4, const float* __restrict__ w5, float* __restrict__ hsW)
{
  __shared__ float hrow[HID];
  int k = blockIdx.x & 127, b = blockIdx.x >> 7;
  int t = threadIdx.x;
  hrow[t] = hs[k * HID + t];
  __syncthreads();
  const float* w = (b < 2) ? w3 : (b < 4) ? w4 : w5;
  const float* row = w + (size_t)t * 512 + (b & 1) * 256;
  float s = 0.f;
  for (int h = 0; h < HID; ++h) s += hrow[h] * row[h];
  hsW[(size_t)k * 1536 + b * 256 + t] = s;
}

__global__ __launch_bounds__(256) void p2b(
    const float* __restrict__ hsW, const float* __restrict__ Kn,
    const float* __restrict__ b3, const float* __restrict__ b4, const float* __restrict__ b5,
    const float* __restrict__ bu3, const float* __restrict__ bu5, float* __restrict__ SG)
{
  __shared__ float kc[NCLS], kr[NCLS];
  int c = blockIdx.x, t = threadIdx.x;
  if (t < NCLS) { kc[t] = Kn[t * NCLS + c]; kr[t] = Kn[c * NCLS + t]; }
  __syncthreads();
  for (int g = 0; g < 3; ++g) {
    int i = t;
    const float* L = hsW + (size_t)(2 * g) * 256 + i;
    const float* R = hsW + (size_t)(2 * g + 1) * 256 + i;
    float s = 0.f;
    for (int k = 0; k < NCLS; ++k) s += kc[k] * L[(size_t)k * 1536] + kr[k] * R[(size_t)k * 1536];
    const float* bg = (g == 0) ? b3 : (g == 1) ? b4 : b5;
    s += bg[i] + ((g < 2) ? bu3[i] : bu5[i]);
    SG[(size_t)c * 768 + g * 256 + i] = s;
  }
}

// ---------------------------------------------------------------------------
extern "C" void kernel_launch(void* const* d_in, const int* in_sizes, int n_in,
                              void* d_out, int out_size, void* d_ws, size_t ws_size,
                              hipStream_t stream) {
  (void)in_sizes; (void)n_in; (void)out_size; (void)ws_size;
  const float* x   = (const float*)d_in[0];
  const float* Kn  = (const float*)d_in[1];
  const float* w3  = (const float*)d_in[2];
  const float* b3  = (const float*)d_in[3];
  const float* u3  = (const float*)d_in[4];
  const float* bu3 = (const float*)d_in[5];
  const float* w4  = (const float*)d_in[6];
  const float* b4  = (const float*)d_in[7];
  const float* w5  = (const float*)d_in[8];
  const float* b5  = (const float*)d_in[9];
  const float* u5  = (const float*)d_in[10];
  const float* bu5 = (const float*)d_in[11];
  float* out = (float*)d_out;

  char* w = (char*)d_ws;
  unsigned short* AVH = (unsigned short*)(w);                 // 131072x512 bf16 (128 MiB)
  unsigned short* PRE = (unsigned short*)(w + 134217728);     // 131072x768 bf16 (192 MiB)
  unsigned short* H1  = (unsigned short*)(w + 335544320);     // 64 MiB
  float*          XW  = (float*)(w + 402653184);              // 1024x1792 fp32
  char* misc = w + 409993216;
  float* S      = (float*)(misc);
  float* hs     = (float*)(misc + 1024);
  float* SW     = (float*)(misc + 132096);
  float* colsum = (float*)(misc + 138240);
  float* rowsum = (float*)(misc + 138752);
  float* hsW    = (float*)(misc + 139264);
  float* SG     = (float*)(misc + 925696);
  unsigned short* WB   = (unsigned short*)(misc + 1318912);
  unsigned short* WB2  = (unsigned short*)(misc + 2498560);
  unsigned short* u5b  = (unsigned short*)(misc + 3416064);
  unsigned short* KbN  = (unsigned short*)(misc + 3547136);
  unsigned short* KTbN = (unsigned short*)(misc + 3579904);
  unsigned short* xb   = (unsigned short*)(misc + 3612672);

  hipMemsetAsync(misc, 0, 132096, stream);  // S + hs

  prep_cast<<<5504, 256, 0, stream>>>(x, Kn, w3, u3, w4, w5, u5, xb, WB, WB2, u5b, KbN, KTbN);
  prep_reduce<<<10, 256, 0, stream>>>(x, Kn, S, colsum, rowsum);
  prep_sw<<<6, 256, 0, stream>>>(S, w3, w4, w5, SW);

  // XW = x @ Wcat^T  [1024,256]x[256,1792] -> fp32
  gemm_bf16<0><<<8 * 14, 256, 0, stream>>>(xb, 256, 256, xb, 256, WB2, 256, 0L,
                                           (void*)XW, 1792, 14, 256, 0xFFFFFFFFu, 8);
  // fused layer 1 -> H1 and AVH (mini-GEMMs in epilogue)
  gemm_l1<<<2048, 256, 0, stream>>>(XW, SW, x, b3, b4, b5, bu3, bu5,
                                    colsum, rowsum, u5b, KTbN, KbN, H1, AVH);

  reduce_hs<<<4096, 256, 0, stream>>>(H1, hs);
  p2a<<<768, 256, 0, stream>>>(hs, w3, w4, w5, hsW);
  p2b<<<128, 256, 0, stream>>>(hsW, Kn, b3, b4, b5, bu3, bu5, SG);

  // PRE: 256x256-tile 4-phase pipelined kernel; ct==1 writes RH (fused l2 prep)
  gemm_pre<<<1536, 512, 0, stream>>>(AVH, H1, WB, SG, PRE);

  // fused layer 2 -> out (streaming GEMM on RH + vectorized epilogue)
  gemm_l2<<<2048, 256, 0, stream>>>(PRE, SG, H1, u5b, out);
}